// Round 1
// baseline (1768.185 us; speedup 1.0000x reference)
//
#include <hip/hip_runtime.h>
#include <cstdint>

#define NN 100000
#define NE 1600000
#define FI 602
#define DD 32
#define CC 41
#define BN_EPS 1e-5f

__device__ __forceinline__ void atomAdd(float* p, float v) {
#ifdef __HIP_PLATFORM_AMD__
  unsafeAtomicAdd(p, v);
#else
  atomicAdd(p, v);
#endif
}

// ---------------- K0: M = lin1_w @ nn1_w1 ; cvec = lin1_b @ nn1_w1 ; zero stats
__global__ __launch_bounds__(256) void k0_prep(
    const float* __restrict__ lin1_w, const float* __restrict__ lin1_b,
    const float* __restrict__ nn1_w1,
    float* __restrict__ M, float* __restrict__ cvec,
    float* __restrict__ stats1, float* __restrict__ stats2) {
  int o = blockIdx.x * 256 + threadIdx.x;
  if (o < FI * DD) {
    int k = o >> 5, j = o & 31;
    float s = 0.f;
    #pragma unroll 4
    for (int c = 0; c < 2 * DD; ++c) s = fmaf(lin1_w[k * (2 * DD) + c], nn1_w1[c * DD + j], s);
    M[o] = s;
  }
  if (blockIdx.x == 0) {
    int t = threadIdx.x;
    if (t < DD) {
      float s = 0.f;
      for (int c = 0; c < 2 * DD; ++c) s = fmaf(lin1_b[c], nn1_w1[c * DD + t], s);
      cvec[t] = s;
    }
    if (t >= 128 && t < 192) stats1[t - 128] = 0.f;
    if (t >= 192) stats2[t - 192] = 0.f;
  }
}

// ---------------- K1: z = x @ M + cvec  (also zero agg)
#define BM 128
#define KT 32
__global__ __launch_bounds__(256) void k1_lin1(
    const float* __restrict__ x, const float* __restrict__ M,
    const float* __restrict__ cvec,
    float* __restrict__ z, float* __restrict__ agg) {
  __shared__ __align__(16) float xs[BM][KT + 4];
  __shared__ __align__(16) float ms[DD][KT + 4];
  const int tid = threadIdx.x;
  const int row0 = blockIdx.x * BM;
  const int tx = tid & 7, ty = tid >> 3;
  float acc[4][4] = {};
  for (int k0 = 0; k0 < FI; k0 += KT) {
    #pragma unroll
    for (int i = 0; i < 16; ++i) {
      int l = tid + i * 256;
      int r = l >> 5, kk = l & 31;
      int gr = row0 + r, gk = k0 + kk;
      float v = 0.f;
      if (gr < NN && gk < FI) v = x[(size_t)gr * FI + gk];
      xs[r][kk] = v;
    }
    #pragma unroll
    for (int i = 0; i < 4; ++i) {
      int e = tid + i * 256;
      int kk = e >> 5, j = e & 31;
      int gk = k0 + kk;
      ms[j][kk] = (gk < FI) ? M[gk * DD + j] : 0.f;
    }
    __syncthreads();
    #pragma unroll
    for (int kk = 0; kk < KT; kk += 4) {
      float4 xa[4], mb[4];
      #pragma unroll
      for (int i = 0; i < 4; ++i) xa[i] = *(const float4*)&xs[ty * 4 + i][kk];
      #pragma unroll
      for (int j = 0; j < 4; ++j) mb[j] = *(const float4*)&ms[tx * 4 + j][kk];
      #pragma unroll
      for (int i = 0; i < 4; ++i)
        #pragma unroll
        for (int j = 0; j < 4; ++j)
          acc[i][j] = fmaf(xa[i].x, mb[j].x,
                      fmaf(xa[i].y, mb[j].y,
                      fmaf(xa[i].z, mb[j].z,
                      fmaf(xa[i].w, mb[j].w, acc[i][j]))));
    }
    __syncthreads();
  }
  float4 cv = *(const float4*)&cvec[tx * 4];
  #pragma unroll
  for (int i = 0; i < 4; ++i) {
    int gr = row0 + ty * 4 + i;
    if (gr >= NN) continue;
    float4 v = make_float4(acc[i][0] + cv.x, acc[i][1] + cv.y,
                           acc[i][2] + cv.z, acc[i][3] + cv.w);
    *(float4*)&z[(size_t)gr * DD + tx * 4] = v;
    *(float4*)&agg[(size_t)gr * DD + tx * 4] = make_float4(0.f, 0.f, 0.f, 0.f);
  }
}

// ---------------- K2: agg[dst] += z[src]
__global__ __launch_bounds__(256) void k2_scatter1(
    const int* __restrict__ ei, const float* __restrict__ z, float* __restrict__ agg) {
  int gid = blockIdx.x * 256 + threadIdx.x;
  int e = gid >> 3, q = gid & 7;
  if (e >= NE) return;
  int s = ei[e], d = ei[NE + e];
  float4 v = *(const float4*)&z[(size_t)s * DD + q * 4];
  float* ap = &agg[(size_t)d * DD + q * 4];
  atomAdd(ap + 0, v.x); atomAdd(ap + 1, v.y); atomAdd(ap + 2, v.z); atomAdd(ap + 3, v.w);
}

// ---------------- K3: g1 = relu(z+agg+b1) @ w2 + b2 ; stats ; zero agg for reuse
__global__ __launch_bounds__(256) void k3_mlp1(
    const float* __restrict__ z, float* __restrict__ agg,
    const float* __restrict__ w2, const float* __restrict__ b1, const float* __restrict__ b2,
    float* __restrict__ g1, float* __restrict__ stats) {
  __shared__ float us[256][DD + 1];
  __shared__ float w2s[DD][DD];
  __shared__ float ps[4][2 * DD];
  const int tid = threadIdx.x;
  const int n0 = blockIdx.x * 256;
  for (int i = tid; i < DD * DD; i += 256) w2s[i >> 5][i & 31] = w2[i];
  #pragma unroll
  for (int i = 0; i < 32; ++i) {
    int l = tid + i * 256;
    int r = l >> 5, c = l & 31;
    float v = 0.f;
    if (n0 + r < NN) {
      size_t gi = (size_t)(n0 + r) * DD + c;
      v = z[gi] + agg[gi];
      agg[gi] = 0.f;
    }
    us[r][c] = v;
  }
  __syncthreads();
  float t[DD];
  #pragma unroll
  for (int k = 0; k < DD; ++k) t[k] = fmaxf(us[tid][k] + b1[k], 0.f);
  float g[DD];
  #pragma unroll
  for (int j = 0; j < DD; ++j) g[j] = b2[j];
  #pragma unroll
  for (int k = 0; k < DD; ++k) {
    float tv = t[k];
    #pragma unroll
    for (int j = 0; j < DD; ++j) g[j] = fmaf(tv, w2s[k][j], g[j]);
  }
  bool valid = (n0 + tid) < NN;
  #pragma unroll
  for (int j = 0; j < DD; ++j) us[tid][j] = g[j];  // own row only: no sync needed
  int wave = tid >> 6, lane = tid & 63;
  #pragma unroll
  for (int j = 0; j < DD; ++j) {
    float v = valid ? g[j] : 0.f;
    float q = v * v;
    #pragma unroll
    for (int off = 1; off < 64; off <<= 1) { v += __shfl_xor(v, off); q += __shfl_xor(q, off); }
    if (lane == 0) { ps[wave][j] = v; ps[wave][DD + j] = q; }
  }
  __syncthreads();
  if (tid < 2 * DD)
    atomAdd(&stats[tid], ps[0][tid] + ps[1][tid] + ps[2][tid] + ps[3][tid]);
  #pragma unroll
  for (int i = 0; i < 32; ++i) {
    int l = tid + i * 256;
    int r = l >> 5, c = l & 31;
    if (n0 + r < NN) g1[(size_t)(n0 + r) * DD + c] = us[r][c];
  }
}

// ---------------- K3b: finalize BN1 params
__global__ void k3b_bn(const float* __restrict__ stats, const float* __restrict__ gamma,
                       const float* __restrict__ beta, float* __restrict__ bnp) {
  int t = threadIdx.x;
  if (t < DD) {
    float mu = stats[t] * (1.f / NN);
    float var = stats[DD + t] * (1.f / NN) - mu * mu;
    bnp[t] = mu;
    bnp[DD + t] = rsqrtf(var + BN_EPS) * gamma[t];
    bnp[2 * DD + t] = beta[t];
  }
}

// ---------------- K5: agg2[dst] += bn1(g1[src])
__global__ __launch_bounds__(256) void k5_scatter2(
    const int* __restrict__ ei, const float* __restrict__ g1,
    const float* __restrict__ bnp, float* __restrict__ agg) {
  int gid = blockIdx.x * 256 + threadIdx.x;
  int e = gid >> 3, q = gid & 7;
  if (e >= NE) return;
  int s = ei[e], d = ei[NE + e];
  float4 g = *(const float4*)&g1[(size_t)s * DD + q * 4];
  float4 mu = *(const float4*)&bnp[q * 4];
  float4 rs = *(const float4*)&bnp[DD + q * 4];
  float4 be = *(const float4*)&bnp[2 * DD + q * 4];
  float4 v = make_float4((g.x - mu.x) * rs.x + be.x, (g.y - mu.y) * rs.y + be.y,
                         (g.z - mu.z) * rs.z + be.z, (g.w - mu.w) * rs.w + be.w);
  float* ap = &agg[(size_t)d * DD + q * 4];
  atomAdd(ap + 0, v.x); atomAdd(ap + 1, v.y); atomAdd(ap + 2, v.z); atomAdd(ap + 3, v.w);
}

// ---------------- K6: g2 = relu((bn1(g1)+agg2)@w1+b1)@w2+b2 ; stats2
__global__ __launch_bounds__(256) void k6_mlp2(
    const float* __restrict__ g1, const float* __restrict__ agg,
    const float* __restrict__ bnp,
    const float* __restrict__ w1, const float* __restrict__ b1,
    const float* __restrict__ w2, const float* __restrict__ b2,
    float* __restrict__ g2, float* __restrict__ stats) {
  __shared__ float us[256][DD + 1];
  __shared__ float w1s[DD][DD];
  __shared__ float w2s[DD][DD];
  __shared__ float ps[4][2 * DD];
  const int tid = threadIdx.x;
  const int n0 = blockIdx.x * 256;
  for (int i = tid; i < DD * DD; i += 256) { w1s[i >> 5][i & 31] = w1[i]; w2s[i >> 5][i & 31] = w2[i]; }
  #pragma unroll
  for (int i = 0; i < 32; ++i) {
    int l = tid + i * 256;
    int r = l >> 5, c = l & 31;
    float v = 0.f;
    if (n0 + r < NN) {
      size_t gi = (size_t)(n0 + r) * DD + c;
      v = (g1[gi] - bnp[c]) * bnp[DD + c] + bnp[2 * DD + c] + agg[gi];
    }
    us[r][c] = v;
  }
  __syncthreads();
  float t1[DD];
  #pragma unroll
  for (int j = 0; j < DD; ++j) t1[j] = b1[j];
  #pragma unroll
  for (int k = 0; k < DD; ++k) {
    float uv = us[tid][k];
    #pragma unroll
    for (int j = 0; j < DD; ++j) t1[j] = fmaf(uv, w1s[k][j], t1[j]);
  }
  #pragma unroll
  for (int j = 0; j < DD; ++j) t1[j] = fmaxf(t1[j], 0.f);
  float g[DD];
  #pragma unroll
  for (int j = 0; j < DD; ++j) g[j] = b2[j];
  #pragma unroll
  for (int k = 0; k < DD; ++k) {
    float tv = t1[k];
    #pragma unroll
    for (int j = 0; j < DD; ++j) g[j] = fmaf(tv, w2s[k][j], g[j]);
  }
  bool valid = (n0 + tid) < NN;
  #pragma unroll
  for (int j = 0; j < DD; ++j) us[tid][j] = g[j];
  int wave = tid >> 6, lane = tid & 63;
  #pragma unroll
  for (int j = 0; j < DD; ++j) {
    float v = valid ? g[j] : 0.f;
    float q = v * v;
    #pragma unroll
    for (int off = 1; off < 64; off <<= 1) { v += __shfl_xor(v, off); q += __shfl_xor(q, off); }
    if (lane == 0) { ps[wave][j] = v; ps[wave][DD + j] = q; }
  }
  __syncthreads();
  if (tid < 2 * DD)
    atomAdd(&stats[tid], ps[0][tid] + ps[1][tid] + ps[2][tid] + ps[3][tid]);
  #pragma unroll
  for (int i = 0; i < 32; ++i) {
    int l = tid + i * 256;
    int r = l >> 5, c = l & 31;
    if (n0 + r < NN) g2[(size_t)(n0 + r) * DD + c] = us[r][c];
  }
}

// ---------------- K7: out = relu(bn2(g2)@fc1+b)@fc2+b
__global__ __launch_bounds__(256) void k7_head(
    const float* __restrict__ g2, const float* __restrict__ stats2,
    const float* __restrict__ bn2_g, const float* __restrict__ bn2_b,
    const float* __restrict__ fc1_w, const float* __restrict__ fc1_b,
    const float* __restrict__ fc2_w, const float* __restrict__ fc2_b,
    float* __restrict__ out) {
  __shared__ float buf[256 * 42];
  __shared__ float fc1s[DD * DD];
  __shared__ float fc2s[DD * CC];
  __shared__ float mu2[DD], rsg2[DD], bet2[DD];
  const int tid = threadIdx.x;
  const int n0 = blockIdx.x * 256;
  if (tid < DD) {
    float mu = stats2[tid] * (1.f / NN);
    float var = stats2[DD + tid] * (1.f / NN) - mu * mu;
    mu2[tid] = mu;
    rsg2[tid] = rsqrtf(var + BN_EPS) * bn2_g[tid];
    bet2[tid] = bn2_b[tid];
  }
  for (int i = tid; i < DD * DD; i += 256) fc1s[i] = fc1_w[i];
  for (int i = tid; i < DD * CC; i += 256) fc2s[i] = fc2_w[i];
  __syncthreads();
  #pragma unroll
  for (int i = 0; i < 32; ++i) {
    int l = tid + i * 256;
    int r = l >> 5, c = l & 31;
    float v = 0.f;
    if (n0 + r < NN) v = (g2[(size_t)(n0 + r) * DD + c] - mu2[c]) * rsg2[c] + bet2[c];
    buf[r * 33 + c] = v;
  }
  __syncthreads();
  float t[DD];
  #pragma unroll
  for (int j = 0; j < DD; ++j) t[j] = fc1_b[j];
  #pragma unroll
  for (int k = 0; k < DD; ++k) {
    float uv = buf[tid * 33 + k];
    #pragma unroll
    for (int j = 0; j < DD; ++j) t[j] = fmaf(uv, fc1s[k * DD + j], t[j]);
  }
  #pragma unroll
  for (int j = 0; j < DD; ++j) t[j] = fmaxf(t[j], 0.f);
  float o[CC];
  #pragma unroll
  for (int j = 0; j < CC; ++j) o[j] = fc2_b[j];
  #pragma unroll
  for (int k = 0; k < DD; ++k) {
    float tv = t[k];
    #pragma unroll
    for (int j = 0; j < CC; ++j) o[j] = fmaf(tv, fc2s[k * CC + j], o[j]);
  }
  __syncthreads();  // done reading buf as input staging
  #pragma unroll
  for (int j = 0; j < CC; ++j) buf[tid * 42 + j] = o[j];
  __syncthreads();
  for (int i = 0; i < CC; ++i) {
    int l = tid + i * 256;
    int r = l / CC, c = l % CC;
    if (n0 + r < NN) out[(size_t)(n0 + r) * CC + c] = buf[r * 42 + c];
  }
}

extern "C" void kernel_launch(void* const* d_in, const int* in_sizes, int n_in,
                              void* d_out, int out_size, void* d_ws, size_t ws_size,
                              hipStream_t stream) {
  const float* x      = (const float*)d_in[0];
  const int*   ei     = (const int*)d_in[1];
  const float* lin1_w = (const float*)d_in[2];
  const float* lin1_b = (const float*)d_in[3];
  const float* nn1_w1 = (const float*)d_in[4];
  const float* nn1_b1 = (const float*)d_in[5];
  const float* nn1_w2 = (const float*)d_in[6];
  const float* nn1_b2 = (const float*)d_in[7];
  const float* bn1_g  = (const float*)d_in[8];
  const float* bn1_b  = (const float*)d_in[9];
  const float* nn2_w1 = (const float*)d_in[10];
  const float* nn2_b1 = (const float*)d_in[11];
  const float* nn2_w2 = (const float*)d_in[12];
  const float* nn2_b2 = (const float*)d_in[13];
  const float* bn2_g  = (const float*)d_in[14];
  const float* bn2_b  = (const float*)d_in[15];
  const float* fc1_w  = (const float*)d_in[16];
  const float* fc1_b  = (const float*)d_in[17];
  const float* fc2_w  = (const float*)d_in[18];
  const float* fc2_b  = (const float*)d_in[19];
  float* out = (float*)d_out;

  float* ws = (float*)d_ws;
  size_t nd = (size_t)NN * DD;
  float* A      = ws;            // z, later g2
  float* B      = ws + nd;       // agg1, later agg2
  float* Cb     = ws + 2 * nd;   // g1
  float* M      = ws + 3 * nd;   // 602*32
  float* cvec   = M + FI * DD;
  float* stats1 = cvec + 32;
  float* bnp1   = stats1 + 64;
  float* stats2 = bnp1 + 96;

  k0_prep<<<(FI * DD + 255) / 256, 256, 0, stream>>>(lin1_w, lin1_b, nn1_w1, M, cvec, stats1, stats2);
  k1_lin1<<<(NN + BM - 1) / BM, 256, 0, stream>>>(x, M, cvec, A, B);
  k2_scatter1<<<(NE * 8) / 256, 256, 0, stream>>>(ei, A, B);
  k3_mlp1<<<(NN + 255) / 256, 256, 0, stream>>>(A, B, nn1_w2, nn1_b1, nn1_b2, Cb, stats1);
  k3b_bn<<<1, 64, 0, stream>>>(stats1, bn1_g, bn1_b, bnp1);
  k5_scatter2<<<(NE * 8) / 256, 256, 0, stream>>>(ei, Cb, bnp1, B);
  k6_mlp2<<<(NN + 255) / 256, 256, 0, stream>>>(Cb, B, bnp1, nn2_w1, nn2_b1, nn2_w2, nn2_b2, A, stats2);
  k7_head<<<(NN + 255) / 256, 256, 0, stream>>>(A, stats2, bn2_g, bn2_b, fc1_w, fc1_b, fc2_w, fc2_b, out);
}

// Round 2
// 974.958 us; speedup vs baseline: 1.8136x; 1.8136x over previous
//
#include <hip/hip_runtime.h>
#include <cstdint>

#define NN 100000
#define NE 1600000
#define FI 602
#define DD 32
#define CC 41
#define BN_EPS 1e-5f

__device__ __forceinline__ void atomAdd(float* p, float v) {
#ifdef __HIP_PLATFORM_AMD__
  unsafeAtomicAdd(p, v);
#else
  atomicAdd(p, v);
#endif
}

// ---------------- K0: M = lin1_w @ nn1_w1 ; cvec = lin1_b @ nn1_w1 ; zero stats
__global__ __launch_bounds__(256) void k0_prep(
    const float* __restrict__ lin1_w, const float* __restrict__ lin1_b,
    const float* __restrict__ nn1_w1,
    float* __restrict__ M, float* __restrict__ cvec,
    float* __restrict__ stats1, float* __restrict__ stats2) {
  int o = blockIdx.x * 256 + threadIdx.x;
  if (o < FI * DD) {
    int k = o >> 5, j = o & 31;
    float s = 0.f;
    #pragma unroll 4
    for (int c = 0; c < 2 * DD; ++c) s = fmaf(lin1_w[k * (2 * DD) + c], nn1_w1[c * DD + j], s);
    M[o] = s;
  }
  if (blockIdx.x == 0) {
    int t = threadIdx.x;
    if (t < DD) {
      float s = 0.f;
      for (int c = 0; c < 2 * DD; ++c) s = fmaf(lin1_b[c], nn1_w1[c * DD + t], s);
      cvec[t] = s;
    }
    if (t >= 128 && t < 192) stats1[t - 128] = 0.f;
    if (t >= 192) stats2[t - 192] = 0.f;
  }
}

// ---------------- CSR build: histogram -> scan -> fill
__global__ __launch_bounds__(256) void k_hist(const int* __restrict__ ei, int* __restrict__ deg) {
  int e = blockIdx.x * 256 + threadIdx.x;
  if (e < NE) atomicAdd(&deg[ei[NE + e]], 1);
}

// one block, 1024 threads: exclusive scan over deg[0..NN-1];
// writes rowstart[0..NN] and resets deg[] (same array reused as fill cursor)
__global__ __launch_bounds__(1024) void k_scan(int* __restrict__ deg_cursor, int* __restrict__ rowstart) {
  __shared__ int ps[1024];
  const int t = threadIdx.x;
  const int CH = (NN + 1023) / 1024;  // 98
  const int beg = t * CH;
  const int end = (beg + CH < NN) ? beg + CH : NN;
  int s = 0;
  for (int i = beg; i < end; ++i) s += deg_cursor[i];
  ps[t] = s;
  __syncthreads();
  for (int off = 1; off < 1024; off <<= 1) {
    int u = (t >= off) ? ps[t - off] : 0;
    __syncthreads();
    ps[t] += u;
    __syncthreads();
  }
  int run = ps[t] - s;  // exclusive base for this chunk
  for (int i = beg; i < end; ++i) {
    int d = deg_cursor[i];
    rowstart[i] = run;
    deg_cursor[i] = run;  // becomes fill cursor
    run += d;
  }
  if (t == 1023) rowstart[NN] = run;
}

__global__ __launch_bounds__(256) void k_fill(const int* __restrict__ ei,
                                              int* __restrict__ cursor,
                                              int* __restrict__ srcidx) {
  int e = blockIdx.x * 256 + threadIdx.x;
  if (e >= NE) return;
  int s = ei[e], d = ei[NE + e];
  int p = atomicAdd(&cursor[d], 1);
  srcidx[p] = s;
}

// ---------------- gather: agg[n] = sum over in-edges of src rows
__global__ __launch_bounds__(256) void k_gather(const int* __restrict__ rowstart,
                                                const int* __restrict__ srcidx,
                                                const float* __restrict__ src,
                                                float* __restrict__ agg) {
  int gid = blockIdx.x * 256 + threadIdx.x;
  int n = gid >> 3, q = gid & 7;
  if (n >= NN) return;
  int beg = rowstart[n], end = rowstart[n + 1];
  float4 acc = make_float4(0.f, 0.f, 0.f, 0.f);
  for (int i = beg; i < end; ++i) {
    int s = srcidx[i];
    float4 v = *(const float4*)&src[(size_t)s * DD + q * 4];
    acc.x += v.x; acc.y += v.y; acc.z += v.z; acc.w += v.w;
  }
  *(float4*)&agg[(size_t)n * DD + q * 4] = acc;
}

// ---------------- K1: z = x @ M + cvec
#define BM 128
#define KT 32
__global__ __launch_bounds__(256) void k1_lin1(
    const float* __restrict__ x, const float* __restrict__ M,
    const float* __restrict__ cvec, float* __restrict__ z) {
  __shared__ __align__(16) float xs[BM][KT + 4];
  __shared__ __align__(16) float ms[DD][KT + 4];
  const int tid = threadIdx.x;
  const int row0 = blockIdx.x * BM;
  const int tx = tid & 7, ty = tid >> 3;
  float acc[4][4] = {};
  for (int k0 = 0; k0 < FI; k0 += KT) {
    #pragma unroll
    for (int i = 0; i < 16; ++i) {
      int l = tid + i * 256;
      int r = l >> 5, kk = l & 31;
      int gr = row0 + r, gk = k0 + kk;
      float v = 0.f;
      if (gr < NN && gk < FI) v = x[(size_t)gr * FI + gk];
      xs[r][kk] = v;
    }
    #pragma unroll
    for (int i = 0; i < 4; ++i) {
      int e = tid + i * 256;
      int kk = e >> 5, j = e & 31;
      int gk = k0 + kk;
      ms[j][kk] = (gk < FI) ? M[gk * DD + j] : 0.f;
    }
    __syncthreads();
    #pragma unroll
    for (int kk = 0; kk < KT; kk += 4) {
      float4 xa[4], mb[4];
      #pragma unroll
      for (int i = 0; i < 4; ++i) xa[i] = *(const float4*)&xs[ty * 4 + i][kk];
      #pragma unroll
      for (int j = 0; j < 4; ++j) mb[j] = *(const float4*)&ms[tx * 4 + j][kk];
      #pragma unroll
      for (int i = 0; i < 4; ++i)
        #pragma unroll
        for (int j = 0; j < 4; ++j)
          acc[i][j] = fmaf(xa[i].x, mb[j].x,
                      fmaf(xa[i].y, mb[j].y,
                      fmaf(xa[i].z, mb[j].z,
                      fmaf(xa[i].w, mb[j].w, acc[i][j]))));
    }
    __syncthreads();
  }
  float4 cv = *(const float4*)&cvec[tx * 4];
  #pragma unroll
  for (int i = 0; i < 4; ++i) {
    int gr = row0 + ty * 4 + i;
    if (gr >= NN) continue;
    float4 v = make_float4(acc[i][0] + cv.x, acc[i][1] + cv.y,
                           acc[i][2] + cv.z, acc[i][3] + cv.w);
    *(float4*)&z[(size_t)gr * DD + tx * 4] = v;
  }
}

// ---------------- K3: g1 = relu(z+agg+b1) @ w2 + b2 ; stats
__global__ __launch_bounds__(256) void k3_mlp1(
    const float* __restrict__ z, const float* __restrict__ agg,
    const float* __restrict__ w2, const float* __restrict__ b1, const float* __restrict__ b2,
    float* __restrict__ g1, float* __restrict__ stats) {
  __shared__ float us[256][DD + 1];
  __shared__ float w2s[DD][DD];
  __shared__ float ps[4][2 * DD];
  const int tid = threadIdx.x;
  const int n0 = blockIdx.x * 256;
  for (int i = tid; i < DD * DD; i += 256) w2s[i >> 5][i & 31] = w2[i];
  #pragma unroll
  for (int i = 0; i < 32; ++i) {
    int l = tid + i * 256;
    int r = l >> 5, c = l & 31;
    float v = 0.f;
    if (n0 + r < NN) {
      size_t gi = (size_t)(n0 + r) * DD + c;
      v = z[gi] + agg[gi];
    }
    us[r][c] = v;
  }
  __syncthreads();
  float t[DD];
  #pragma unroll
  for (int k = 0; k < DD; ++k) t[k] = fmaxf(us[tid][k] + b1[k], 0.f);
  float g[DD];
  #pragma unroll
  for (int j = 0; j < DD; ++j) g[j] = b2[j];
  #pragma unroll
  for (int k = 0; k < DD; ++k) {
    float tv = t[k];
    #pragma unroll
    for (int j = 0; j < DD; ++j) g[j] = fmaf(tv, w2s[k][j], g[j]);
  }
  bool valid = (n0 + tid) < NN;
  #pragma unroll
  for (int j = 0; j < DD; ++j) us[tid][j] = g[j];
  int wave = tid >> 6, lane = tid & 63;
  #pragma unroll
  for (int j = 0; j < DD; ++j) {
    float v = valid ? g[j] : 0.f;
    float q = v * v;
    #pragma unroll
    for (int off = 1; off < 64; off <<= 1) { v += __shfl_xor(v, off); q += __shfl_xor(q, off); }
    if (lane == 0) { ps[wave][j] = v; ps[wave][DD + j] = q; }
  }
  __syncthreads();
  if (tid < 2 * DD)
    atomAdd(&stats[tid], ps[0][tid] + ps[1][tid] + ps[2][tid] + ps[3][tid]);
  #pragma unroll
  for (int i = 0; i < 32; ++i) {
    int l = tid + i * 256;
    int r = l >> 5, c = l & 31;
    if (n0 + r < NN) g1[(size_t)(n0 + r) * DD + c] = us[r][c];
  }
}

// ---------------- K3b: finalize BN1 params
__global__ void k3b_bn(const float* __restrict__ stats, const float* __restrict__ gamma,
                       const float* __restrict__ beta, float* __restrict__ bnp) {
  int t = threadIdx.x;
  if (t < DD) {
    float mu = stats[t] * (1.f / NN);
    float var = stats[DD + t] * (1.f / NN) - mu * mu;
    bnp[t] = mu;
    bnp[DD + t] = rsqrtf(var + BN_EPS) * gamma[t];
    bnp[2 * DD + t] = beta[t];
  }
}

// ---------------- K4: h1 = bn1(g1)  (materialize once; feeds gather2 and k6)
__global__ __launch_bounds__(256) void k4_bnapply(
    const float* __restrict__ g1, const float* __restrict__ bnp, float* __restrict__ h1) {
  int i4 = blockIdx.x * 256 + threadIdx.x;      // float4 index over N*D/4
  if (i4 >= NN * DD / 4) return;
  int q = i4 & 7;
  float4 g = *(const float4*)&g1[(size_t)i4 * 4];
  float4 mu = *(const float4*)&bnp[q * 4];
  float4 rs = *(const float4*)&bnp[DD + q * 4];
  float4 be = *(const float4*)&bnp[2 * DD + q * 4];
  float4 v = make_float4((g.x - mu.x) * rs.x + be.x, (g.y - mu.y) * rs.y + be.y,
                         (g.z - mu.z) * rs.z + be.z, (g.w - mu.w) * rs.w + be.w);
  *(float4*)&h1[(size_t)i4 * 4] = v;
}

// ---------------- K6: g2 = relu((h1+agg2)@w1+b1)@w2+b2 ; stats2
__global__ __launch_bounds__(256) void k6_mlp2(
    const float* __restrict__ h1, const float* __restrict__ agg,
    const float* __restrict__ w1, const float* __restrict__ b1,
    const float* __restrict__ w2, const float* __restrict__ b2,
    float* __restrict__ g2, float* __restrict__ stats) {
  __shared__ float us[256][DD + 1];
  __shared__ float w1s[DD][DD];
  __shared__ float w2s[DD][DD];
  __shared__ float ps[4][2 * DD];
  const int tid = threadIdx.x;
  const int n0 = blockIdx.x * 256;
  for (int i = tid; i < DD * DD; i += 256) { w1s[i >> 5][i & 31] = w1[i]; w2s[i >> 5][i & 31] = w2[i]; }
  #pragma unroll
  for (int i = 0; i < 32; ++i) {
    int l = tid + i * 256;
    int r = l >> 5, c = l & 31;
    float v = 0.f;
    if (n0 + r < NN) {
      size_t gi = (size_t)(n0 + r) * DD + c;
      v = h1[gi] + agg[gi];
    }
    us[r][c] = v;
  }
  __syncthreads();
  float t1[DD];
  #pragma unroll
  for (int j = 0; j < DD; ++j) t1[j] = b1[j];
  #pragma unroll
  for (int k = 0; k < DD; ++k) {
    float uv = us[tid][k];
    #pragma unroll
    for (int j = 0; j < DD; ++j) t1[j] = fmaf(uv, w1s[k][j], t1[j]);
  }
  #pragma unroll
  for (int j = 0; j < DD; ++j) t1[j] = fmaxf(t1[j], 0.f);
  float g[DD];
  #pragma unroll
  for (int j = 0; j < DD; ++j) g[j] = b2[j];
  #pragma unroll
  for (int k = 0; k < DD; ++k) {
    float tv = t1[k];
    #pragma unroll
    for (int j = 0; j < DD; ++j) g[j] = fmaf(tv, w2s[k][j], g[j]);
  }
  bool valid = (n0 + tid) < NN;
  #pragma unroll
  for (int j = 0; j < DD; ++j) us[tid][j] = g[j];
  int wave = tid >> 6, lane = tid & 63;
  #pragma unroll
  for (int j = 0; j < DD; ++j) {
    float v = valid ? g[j] : 0.f;
    float q = v * v;
    #pragma unroll
    for (int off = 1; off < 64; off <<= 1) { v += __shfl_xor(v, off); q += __shfl_xor(q, off); }
    if (lane == 0) { ps[wave][j] = v; ps[wave][DD + j] = q; }
  }
  __syncthreads();
  if (tid < 2 * DD)
    atomAdd(&stats[tid], ps[0][tid] + ps[1][tid] + ps[2][tid] + ps[3][tid]);
  #pragma unroll
  for (int i = 0; i < 32; ++i) {
    int l = tid + i * 256;
    int r = l >> 5, c = l & 31;
    if (n0 + r < NN) g2[(size_t)(n0 + r) * DD + c] = us[r][c];
  }
}

// ---------------- K7: out = relu(bn2(g2)@fc1+b)@fc2+b
__global__ __launch_bounds__(256) void k7_head(
    const float* __restrict__ g2, const float* __restrict__ stats2,
    const float* __restrict__ bn2_g, const float* __restrict__ bn2_b,
    const float* __restrict__ fc1_w, const float* __restrict__ fc1_b,
    const float* __restrict__ fc2_w, const float* __restrict__ fc2_b,
    float* __restrict__ out) {
  __shared__ float buf[256 * 42];
  __shared__ float fc1s[DD * DD];
  __shared__ float fc2s[DD * CC];
  __shared__ float mu2[DD], rsg2[DD], bet2[DD];
  const int tid = threadIdx.x;
  const int n0 = blockIdx.x * 256;
  if (tid < DD) {
    float mu = stats2[tid] * (1.f / NN);
    float var = stats2[DD + tid] * (1.f / NN) - mu * mu;
    mu2[tid] = mu;
    rsg2[tid] = rsqrtf(var + BN_EPS) * bn2_g[tid];
    bet2[tid] = bn2_b[tid];
  }
  for (int i = tid; i < DD * DD; i += 256) fc1s[i] = fc1_w[i];
  for (int i = tid; i < DD * CC; i += 256) fc2s[i] = fc2_w[i];
  __syncthreads();
  #pragma unroll
  for (int i = 0; i < 32; ++i) {
    int l = tid + i * 256;
    int r = l >> 5, c = l & 31;
    float v = 0.f;
    if (n0 + r < NN) v = (g2[(size_t)(n0 + r) * DD + c] - mu2[c]) * rsg2[c] + bet2[c];
    buf[r * 33 + c] = v;
  }
  __syncthreads();
  float t[DD];
  #pragma unroll
  for (int j = 0; j < DD; ++j) t[j] = fc1_b[j];
  #pragma unroll
  for (int k = 0; k < DD; ++k) {
    float uv = buf[tid * 33 + k];
    #pragma unroll
    for (int j = 0; j < DD; ++j) t[j] = fmaf(uv, fc1s[k * DD + j], t[j]);
  }
  #pragma unroll
  for (int j = 0; j < DD; ++j) t[j] = fmaxf(t[j], 0.f);
  float o[CC];
  #pragma unroll
  for (int j = 0; j < CC; ++j) o[j] = fc2_b[j];
  #pragma unroll
  for (int k = 0; k < DD; ++k) {
    float tv = t[k];
    #pragma unroll
    for (int j = 0; j < CC; ++j) o[j] = fmaf(tv, fc2s[k * CC + j], o[j]);
  }
  __syncthreads();
  #pragma unroll
  for (int j = 0; j < CC; ++j) buf[tid * 42 + j] = o[j];
  __syncthreads();
  for (int i = 0; i < CC; ++i) {
    int l = tid + i * 256;
    int r = l / CC, c = l % CC;
    if (n0 + r < NN) out[(size_t)(n0 + r) * CC + c] = buf[r * 42 + c];
  }
}

extern "C" void kernel_launch(void* const* d_in, const int* in_sizes, int n_in,
                              void* d_out, int out_size, void* d_ws, size_t ws_size,
                              hipStream_t stream) {
  const float* x      = (const float*)d_in[0];
  const int*   ei     = (const int*)d_in[1];
  const float* lin1_w = (const float*)d_in[2];
  const float* lin1_b = (const float*)d_in[3];
  const float* nn1_w1 = (const float*)d_in[4];
  const float* nn1_b1 = (const float*)d_in[5];
  const float* nn1_w2 = (const float*)d_in[6];
  const float* nn1_b2 = (const float*)d_in[7];
  const float* bn1_g  = (const float*)d_in[8];
  const float* bn1_b  = (const float*)d_in[9];
  const float* nn2_w1 = (const float*)d_in[10];
  const float* nn2_b1 = (const float*)d_in[11];
  const float* nn2_w2 = (const float*)d_in[12];
  const float* nn2_b2 = (const float*)d_in[13];
  const float* bn2_g  = (const float*)d_in[14];
  const float* bn2_b  = (const float*)d_in[15];
  const float* fc1_w  = (const float*)d_in[16];
  const float* fc1_b  = (const float*)d_in[17];
  const float* fc2_w  = (const float*)d_in[18];
  const float* fc2_b  = (const float*)d_in[19];
  float* out = (float*)d_out;

  float* ws = (float*)d_ws;
  size_t nd = (size_t)NN * DD;
  float* A      = ws;            // z, then h1=bn1(g1)
  float* B      = ws + nd;       // agg1, then agg2
  float* Cb     = ws + 2 * nd;   // g1, then g2
  float* M      = ws + 3 * nd;   // 602*32
  float* cvec   = M + FI * DD;
  float* stats1 = cvec + 32;
  float* bnp1   = stats1 + 64;
  float* stats2 = bnp1 + 96;
  int*   rowstart = (int*)(stats2 + 64);         // NN+1
  int*   cursor   = rowstart + (NN + 1);         // NN (deg, then fill cursor)
  int*   srcidx   = cursor + NN;                 // NE

  // CSR build
  hipMemsetAsync(cursor, 0, NN * sizeof(int), stream);
  k_hist<<<(NE + 255) / 256, 256, 0, stream>>>(ei, cursor);
  k_scan<<<1, 1024, 0, stream>>>(cursor, rowstart);
  k_fill<<<(NE + 255) / 256, 256, 0, stream>>>(ei, cursor, srcidx);

  k0_prep<<<(FI * DD + 255) / 256, 256, 0, stream>>>(lin1_w, lin1_b, nn1_w1, M, cvec, stats1, stats2);
  k1_lin1<<<(NN + BM - 1) / BM, 256, 0, stream>>>(x, M, cvec, A);
  k_gather<<<(NN * 8 + 255) / 256, 256, 0, stream>>>(rowstart, srcidx, A, B);
  k3_mlp1<<<(NN + 255) / 256, 256, 0, stream>>>(A, B, nn1_w2, nn1_b1, nn1_b2, Cb, stats1);
  k3b_bn<<<1, 64, 0, stream>>>(stats1, bn1_g, bn1_b, bnp1);
  k4_bnapply<<<(NN * DD / 4 + 255) / 256, 256, 0, stream>>>(Cb, bnp1, A);
  k_gather<<<(NN * 8 + 255) / 256, 256, 0, stream>>>(rowstart, srcidx, A, B);
  k6_mlp2<<<(NN + 255) / 256, 256, 0, stream>>>(A, B, nn2_w1, nn2_b1, nn2_w2, nn2_b2, Cb, stats2);
  k7_head<<<(NN + 255) / 256, 256, 0, stream>>>(Cb, stats2, bn2_g, bn2_b, fc1_w, fc1_b, fc2_w, fc2_b, out);
}

// Round 3
// 748.901 us; speedup vs baseline: 2.3610x; 1.3019x over previous
//
#include <hip/hip_runtime.h>
#include <cstdint>

#define NN 100000
#define NE 1600000
#define FI 602
#define FIP 640           // padded K for k1 (zero rows 602..639)
#define KH 320            // k-range per half
#define DD 32
#define CC 41
#define BN_EPS 1e-5f

__device__ __forceinline__ void atomAdd(float* p, float v) {
#ifdef __HIP_PLATFORM_AMD__
  unsafeAtomicAdd(p, v);
#else
  atomicAdd(p, v);
#endif
}

// ---------------- K0: Mp[640x32] = lin1_w @ nn1_w1 (zero-padded) ; cvec ; zero stats
__global__ __launch_bounds__(256) void k0_prep(
    const float* __restrict__ lin1_w, const float* __restrict__ lin1_b,
    const float* __restrict__ nn1_w1,
    float* __restrict__ Mp, float* __restrict__ cvec,
    float* __restrict__ stats1, float* __restrict__ stats2) {
  int o = blockIdx.x * 256 + threadIdx.x;   // grid covers FIP*DD
  if (o < FIP * DD) {
    int k = o >> 5, j = o & 31;
    float s = 0.f;
    if (k < FI) {
      #pragma unroll 4
      for (int c = 0; c < 2 * DD; ++c) s = fmaf(lin1_w[k * (2 * DD) + c], nn1_w1[c * DD + j], s);
    }
    Mp[o] = s;
  }
  if (blockIdx.x == 0) {
    int t = threadIdx.x;
    if (t < DD) {
      float s = 0.f;
      for (int c = 0; c < 2 * DD; ++c) s = fmaf(lin1_b[c], nn1_w1[c * DD + t], s);
      cvec[t] = s;
    }
    if (t >= 128 && t < 192) stats1[t - 128] = 0.f;
    if (t >= 192) stats2[t - 192] = 0.f;
  }
}

// ---------------- CSR build: histogram -> scan -> fill
__global__ __launch_bounds__(256) void k_hist(const int* __restrict__ ei, int* __restrict__ deg) {
  int e = blockIdx.x * 256 + threadIdx.x;
  if (e < NE) atomicAdd(&deg[ei[NE + e]], 1);
}

__global__ __launch_bounds__(1024) void k_scan(int* __restrict__ deg_cursor, int* __restrict__ rowstart) {
  __shared__ int ps[1024];
  const int t = threadIdx.x;
  const int CH = (NN + 1023) / 1024;
  const int beg = t * CH;
  const int end = (beg + CH < NN) ? beg + CH : NN;
  int s = 0;
  for (int i = beg; i < end; ++i) s += deg_cursor[i];
  ps[t] = s;
  __syncthreads();
  for (int off = 1; off < 1024; off <<= 1) {
    int u = (t >= off) ? ps[t - off] : 0;
    __syncthreads();
    ps[t] += u;
    __syncthreads();
  }
  int run = ps[t] - s;
  for (int i = beg; i < end; ++i) {
    int d = deg_cursor[i];
    rowstart[i] = run;
    deg_cursor[i] = run;
    run += d;
  }
  if (t == 1023) rowstart[NN] = run;
}

__global__ __launch_bounds__(256) void k_fill(const int* __restrict__ ei,
                                              int* __restrict__ cursor,
                                              int* __restrict__ srcidx) {
  int e = blockIdx.x * 256 + threadIdx.x;
  if (e >= NE) return;
  int s = ei[e], d = ei[NE + e];
  int p = atomicAdd(&cursor[d], 1);
  srcidx[p] = s;
}

// ---------------- gather: agg[n] = sum of src rows over in-edges (4-deep pipelined)
__global__ __launch_bounds__(256) void k_gather(const int* __restrict__ rowstart,
                                                const int* __restrict__ srcidx,
                                                const float* __restrict__ src,
                                                float* __restrict__ agg) {
  int gid = blockIdx.x * 256 + threadIdx.x;
  int n = gid >> 3, q = gid & 7;
  if (n >= NN) return;
  int beg = rowstart[n], end = rowstart[n + 1];
  float4 a0 = make_float4(0.f, 0.f, 0.f, 0.f);
  float4 a1 = a0, a2 = a0, a3 = a0;
  int i = beg;
  for (; i + 4 <= end; i += 4) {
    int s0 = srcidx[i], s1 = srcidx[i + 1], s2 = srcidx[i + 2], s3 = srcidx[i + 3];
    float4 v0 = *(const float4*)&src[(size_t)s0 * DD + q * 4];
    float4 v1 = *(const float4*)&src[(size_t)s1 * DD + q * 4];
    float4 v2 = *(const float4*)&src[(size_t)s2 * DD + q * 4];
    float4 v3 = *(const float4*)&src[(size_t)s3 * DD + q * 4];
    a0.x += v0.x; a0.y += v0.y; a0.z += v0.z; a0.w += v0.w;
    a1.x += v1.x; a1.y += v1.y; a1.z += v1.z; a1.w += v1.w;
    a2.x += v2.x; a2.y += v2.y; a2.z += v2.z; a2.w += v2.w;
    a3.x += v3.x; a3.y += v3.y; a3.z += v3.z; a3.w += v3.w;
  }
  for (; i < end; ++i) {
    int s0 = srcidx[i];
    float4 v0 = *(const float4*)&src[(size_t)s0 * DD + q * 4];
    a0.x += v0.x; a0.y += v0.y; a0.z += v0.z; a0.w += v0.w;
  }
  float4 r = make_float4(a0.x + a1.x + a2.x + a3.x, a0.y + a1.y + a2.y + a3.y,
                         a0.z + a1.z + a2.z + a3.z, a0.w + a1.w + a2.w + a3.w);
  *(float4*)&agg[(size_t)n * DD + q * 4] = r;
}

// ---------------- K1 v2: z = x @ Mp + cvec
// 128 rows/block, 256 threads: thread = (row r = tid&127, k-half h = tid>>7).
// x chunk staged in LDS (coalesced float2); M row broadcast via readfirstlane -> s_load.
__global__ __launch_bounds__(256) void k1_lin1(
    const float* __restrict__ x, const float* __restrict__ Mp,
    const float* __restrict__ cvec, float* __restrict__ z) {
  __shared__ float xs[2][128][33];
  const int tid = threadIdx.x;
  const int r = tid & 127;
  const int h = tid >> 7;
  const int row = blockIdx.x * 128 + r;
  float acc[DD] = {};
  for (int c = 0; c < 10; ++c) {
    #pragma unroll
    for (int i = 0; i < 16; ++i) {
      int fid = i * 256 + tid;          // float2 slot: 2 tiles x 128 rows x 16 pairs
      int tile = fid >> 11;
      int e = fid & 2047;
      int rr = e >> 4, kp = e & 15;
      int grow = blockIdx.x * 128 + rr;
      int gk = tile * KH + c * 32 + kp * 2;
      float2 v = make_float2(0.f, 0.f);
      if (grow < NN && gk < FI) v = *(const float2*)&x[(size_t)grow * FI + gk];
      xs[tile][rr][kp * 2] = v.x;
      xs[tile][rr][kp * 2 + 1] = v.y;
    }
    __syncthreads();
    #pragma unroll
    for (int kk = 0; kk < 32; ++kk) {
      float xv = xs[h][r][kk];
      int kg = __builtin_amdgcn_readfirstlane(h * KH + c * 32 + kk);
      const float* Mk = Mp + (size_t)kg * DD;
      #pragma unroll
      for (int j = 0; j < DD; ++j) acc[j] = fmaf(xv, Mk[j], acc[j]);
    }
    __syncthreads();
  }
  // combine halves through LDS
  float* psf = &xs[0][0][0];
  if (h == 1) {
    #pragma unroll
    for (int j = 0; j < DD; ++j) psf[r * 33 + j] = acc[j];
  }
  __syncthreads();
  if (h == 0 && row < NN) {
    #pragma unroll
    for (int j = 0; j < DD; ++j) acc[j] += psf[r * 33 + j] + cvec[j];
    #pragma unroll
    for (int j4 = 0; j4 < 8; ++j4)
      *(float4*)&z[(size_t)row * DD + j4 * 4] =
          make_float4(acc[j4 * 4], acc[j4 * 4 + 1], acc[j4 * 4 + 2], acc[j4 * 4 + 3]);
  }
}

// ---------------- K3: g1 = relu(z+agg+b1) @ w2 + b2 ; stats
__global__ __launch_bounds__(256) void k3_mlp1(
    const float* __restrict__ z, const float* __restrict__ agg,
    const float* __restrict__ w2, const float* __restrict__ b1, const float* __restrict__ b2,
    float* __restrict__ g1, float* __restrict__ stats) {
  __shared__ float us[256][DD + 1];
  __shared__ float w2s[DD][DD];
  __shared__ float ps[4][2 * DD];
  const int tid = threadIdx.x;
  const int n0 = blockIdx.x * 256;
  for (int i = tid; i < DD * DD; i += 256) w2s[i >> 5][i & 31] = w2[i];
  #pragma unroll
  for (int i = 0; i < 32; ++i) {
    int l = tid + i * 256;
    int r = l >> 5, c = l & 31;
    float v = 0.f;
    if (n0 + r < NN) {
      size_t gi = (size_t)(n0 + r) * DD + c;
      v = z[gi] + agg[gi];
    }
    us[r][c] = v;
  }
  __syncthreads();
  float t[DD];
  #pragma unroll
  for (int k = 0; k < DD; ++k) t[k] = fmaxf(us[tid][k] + b1[k], 0.f);
  float g[DD];
  #pragma unroll
  for (int j = 0; j < DD; ++j) g[j] = b2[j];
  #pragma unroll
  for (int k = 0; k < DD; ++k) {
    float tv = t[k];
    #pragma unroll
    for (int j = 0; j < DD; ++j) g[j] = fmaf(tv, w2s[k][j], g[j]);
  }
  bool valid = (n0 + tid) < NN;
  #pragma unroll
  for (int j = 0; j < DD; ++j) us[tid][j] = g[j];
  int wave = tid >> 6, lane = tid & 63;
  #pragma unroll
  for (int j = 0; j < DD; ++j) {
    float v = valid ? g[j] : 0.f;
    float q = v * v;
    #pragma unroll
    for (int off = 1; off < 64; off <<= 1) { v += __shfl_xor(v, off); q += __shfl_xor(q, off); }
    if (lane == 0) { ps[wave][j] = v; ps[wave][DD + j] = q; }
  }
  __syncthreads();
  if (tid < 2 * DD)
    atomAdd(&stats[tid], ps[0][tid] + ps[1][tid] + ps[2][tid] + ps[3][tid]);
  #pragma unroll
  for (int i = 0; i < 32; ++i) {
    int l = tid + i * 256;
    int r = l >> 5, c = l & 31;
    if (n0 + r < NN) g1[(size_t)(n0 + r) * DD + c] = us[r][c];
  }
}

// ---------------- K3b: finalize BN1 params
__global__ void k3b_bn(const float* __restrict__ stats, const float* __restrict__ gamma,
                       const float* __restrict__ beta, float* __restrict__ bnp) {
  int t = threadIdx.x;
  if (t < DD) {
    float mu = stats[t] * (1.f / NN);
    float var = stats[DD + t] * (1.f / NN) - mu * mu;
    bnp[t] = mu;
    bnp[DD + t] = rsqrtf(var + BN_EPS) * gamma[t];
    bnp[2 * DD + t] = beta[t];
  }
}

// ---------------- K4: h1 = bn1(g1)
__global__ __launch_bounds__(256) void k4_bnapply(
    const float* __restrict__ g1, const float* __restrict__ bnp, float* __restrict__ h1) {
  int i4 = blockIdx.x * 256 + threadIdx.x;
  if (i4 >= NN * DD / 4) return;
  int q = i4 & 7;
  float4 g = *(const float4*)&g1[(size_t)i4 * 4];
  float4 mu = *(const float4*)&bnp[q * 4];
  float4 rs = *(const float4*)&bnp[DD + q * 4];
  float4 be = *(const float4*)&bnp[2 * DD + q * 4];
  float4 v = make_float4((g.x - mu.x) * rs.x + be.x, (g.y - mu.y) * rs.y + be.y,
                         (g.z - mu.z) * rs.z + be.z, (g.w - mu.w) * rs.w + be.w);
  *(float4*)&h1[(size_t)i4 * 4] = v;
}

// ---------------- K6: g2 = relu((h1+agg2)@w1+b1)@w2+b2 ; stats2
__global__ __launch_bounds__(256) void k6_mlp2(
    const float* __restrict__ h1, const float* __restrict__ agg,
    const float* __restrict__ w1, const float* __restrict__ b1,
    const float* __restrict__ w2, const float* __restrict__ b2,
    float* __restrict__ g2, float* __restrict__ stats) {
  __shared__ float us[256][DD + 1];
  __shared__ float w1s[DD][DD];
  __shared__ float w2s[DD][DD];
  __shared__ float ps[4][2 * DD];
  const int tid = threadIdx.x;
  const int n0 = blockIdx.x * 256;
  for (int i = tid; i < DD * DD; i += 256) { w1s[i >> 5][i & 31] = w1[i]; w2s[i >> 5][i & 31] = w2[i]; }
  #pragma unroll
  for (int i = 0; i < 32; ++i) {
    int l = tid + i * 256;
    int r = l >> 5, c = l & 31;
    float v = 0.f;
    if (n0 + r < NN) {
      size_t gi = (size_t)(n0 + r) * DD + c;
      v = h1[gi] + agg[gi];
    }
    us[r][c] = v;
  }
  __syncthreads();
  float t1[DD];
  #pragma unroll
  for (int j = 0; j < DD; ++j) t1[j] = b1[j];
  #pragma unroll
  for (int k = 0; k < DD; ++k) {
    float uv = us[tid][k];
    #pragma unroll
    for (int j = 0; j < DD; ++j) t1[j] = fmaf(uv, w1s[k][j], t1[j]);
  }
  #pragma unroll
  for (int j = 0; j < DD; ++j) t1[j] = fmaxf(t1[j], 0.f);
  float g[DD];
  #pragma unroll
  for (int j = 0; j < DD; ++j) g[j] = b2[j];
  #pragma unroll
  for (int k = 0; k < DD; ++k) {
    float tv = t1[k];
    #pragma unroll
    for (int j = 0; j < DD; ++j) g[j] = fmaf(tv, w2s[k][j], g[j]);
  }
  bool valid = (n0 + tid) < NN;
  #pragma unroll
  for (int j = 0; j < DD; ++j) us[tid][j] = g[j];
  int wave = tid >> 6, lane = tid & 63;
  #pragma unroll
  for (int j = 0; j < DD; ++j) {
    float v = valid ? g[j] : 0.f;
    float q = v * v;
    #pragma unroll
    for (int off = 1; off < 64; off <<= 1) { v += __shfl_xor(v, off); q += __shfl_xor(q, off); }
    if (lane == 0) { ps[wave][j] = v; ps[wave][DD + j] = q; }
  }
  __syncthreads();
  if (tid < 2 * DD)
    atomAdd(&stats[tid], ps[0][tid] + ps[1][tid] + ps[2][tid] + ps[3][tid]);
  #pragma unroll
  for (int i = 0; i < 32; ++i) {
    int l = tid + i * 256;
    int r = l >> 5, c = l & 31;
    if (n0 + r < NN) g2[(size_t)(n0 + r) * DD + c] = us[r][c];
  }
}

// ---------------- K7: out = relu(bn2(g2)@fc1+b)@fc2+b
__global__ __launch_bounds__(256) void k7_head(
    const float* __restrict__ g2, const float* __restrict__ stats2,
    const float* __restrict__ bn2_g, const float* __restrict__ bn2_b,
    const float* __restrict__ fc1_w, const float* __restrict__ fc1_b,
    const float* __restrict__ fc2_w, const float* __restrict__ fc2_b,
    float* __restrict__ out) {
  __shared__ float buf[256 * 42];
  __shared__ float fc1s[DD * DD];
  __shared__ float fc2s[DD * CC];
  __shared__ float mu2[DD], rsg2[DD], bet2[DD];
  const int tid = threadIdx.x;
  const int n0 = blockIdx.x * 256;
  if (tid < DD) {
    float mu = stats2[tid] * (1.f / NN);
    float var = stats2[DD + tid] * (1.f / NN) - mu * mu;
    mu2[tid] = mu;
    rsg2[tid] = rsqrtf(var + BN_EPS) * bn2_g[tid];
    bet2[tid] = bn2_b[tid];
  }
  for (int i = tid; i < DD * DD; i += 256) fc1s[i] = fc1_w[i];
  for (int i = tid; i < DD * CC; i += 256) fc2s[i] = fc2_w[i];
  __syncthreads();
  #pragma unroll
  for (int i = 0; i < 32; ++i) {
    int l = tid + i * 256;
    int r = l >> 5, c = l & 31;
    float v = 0.f;
    if (n0 + r < NN) v = (g2[(size_t)(n0 + r) * DD + c] - mu2[c]) * rsg2[c] + bet2[c];
    buf[r * 33 + c] = v;
  }
  __syncthreads();
  float t[DD];
  #pragma unroll
  for (int j = 0; j < DD; ++j) t[j] = fc1_b[j];
  #pragma unroll
  for (int k = 0; k < DD; ++k) {
    float uv = buf[tid * 33 + k];
    #pragma unroll
    for (int j = 0; j < DD; ++j) t[j] = fmaf(uv, fc1s[k * DD + j], t[j]);
  }
  #pragma unroll
  for (int j = 0; j < DD; ++j) t[j] = fmaxf(t[j], 0.f);
  float o[CC];
  #pragma unroll
  for (int j = 0; j < CC; ++j) o[j] = fc2_b[j];
  #pragma unroll
  for (int k = 0; k < DD; ++k) {
    float tv = t[k];
    #pragma unroll
    for (int j = 0; j < CC; ++j) o[j] = fmaf(tv, fc2s[k * CC + j], o[j]);
  }
  __syncthreads();
  #pragma unroll
  for (int j = 0; j < CC; ++j) buf[tid * 42 + j] = o[j];
  __syncthreads();
  for (int i = 0; i < CC; ++i) {
    int l = tid + i * 256;
    int r = l / CC, c = l % CC;
    if (n0 + r < NN) out[(size_t)(n0 + r) * CC + c] = buf[r * 42 + c];
  }
}

extern "C" void kernel_launch(void* const* d_in, const int* in_sizes, int n_in,
                              void* d_out, int out_size, void* d_ws, size_t ws_size,
                              hipStream_t stream) {
  const float* x      = (const float*)d_in[0];
  const int*   ei     = (const int*)d_in[1];
  const float* lin1_w = (const float*)d_in[2];
  const float* lin1_b = (const float*)d_in[3];
  const float* nn1_w1 = (const float*)d_in[4];
  const float* nn1_b1 = (const float*)d_in[5];
  const float* nn1_w2 = (const float*)d_in[6];
  const float* nn1_b2 = (const float*)d_in[7];
  const float* bn1_g  = (const float*)d_in[8];
  const float* bn1_b  = (const float*)d_in[9];
  const float* nn2_w1 = (const float*)d_in[10];
  const float* nn2_b1 = (const float*)d_in[11];
  const float* nn2_w2 = (const float*)d_in[12];
  const float* nn2_b2 = (const float*)d_in[13];
  const float* bn2_g  = (const float*)d_in[14];
  const float* bn2_b  = (const float*)d_in[15];
  const float* fc1_w  = (const float*)d_in[16];
  const float* fc1_b  = (const float*)d_in[17];
  const float* fc2_w  = (const float*)d_in[18];
  const float* fc2_b  = (const float*)d_in[19];
  float* out = (float*)d_out;

  float* ws = (float*)d_ws;
  size_t nd = (size_t)NN * DD;
  float* A      = ws;            // z, then h1=bn1(g1)
  float* B      = ws + nd;       // agg1, then agg2
  float* Cb     = ws + 2 * nd;   // g1, then g2
  float* Mp     = ws + 3 * nd;   // 640*32 (padded)
  float* cvec   = Mp + FIP * DD;
  float* stats1 = cvec + 32;
  float* bnp1   = stats1 + 64;
  float* stats2 = bnp1 + 96;
  int*   rowstart = (int*)(stats2 + 64);         // NN+1
  int*   cursor   = rowstart + (NN + 1);         // NN
  int*   srcidx   = cursor + NN;                 // NE

  // CSR build
  hipMemsetAsync(cursor, 0, NN * sizeof(int), stream);
  k_hist<<<(NE + 255) / 256, 256, 0, stream>>>(ei, cursor);
  k_scan<<<1, 1024, 0, stream>>>(cursor, rowstart);
  k_fill<<<(NE + 255) / 256, 256, 0, stream>>>(ei, cursor, srcidx);

  k0_prep<<<(FIP * DD + 255) / 256, 256, 0, stream>>>(lin1_w, lin1_b, nn1_w1, Mp, cvec, stats1, stats2);
  k1_lin1<<<(NN + 127) / 128, 256, 0, stream>>>(x, Mp, cvec, A);
  k_gather<<<(NN * 8 + 255) / 256, 256, 0, stream>>>(rowstart, srcidx, A, B);
  k3_mlp1<<<(NN + 255) / 256, 256, 0, stream>>>(A, B, nn1_w2, nn1_b1, nn1_b2, Cb, stats1);
  k3b_bn<<<1, 64, 0, stream>>>(stats1, bn1_g, bn1_b, bnp1);
  k4_bnapply<<<(NN * DD / 4 + 255) / 256, 256, 0, stream>>>(Cb, bnp1, A);
  k_gather<<<(NN * 8 + 255) / 256, 256, 0, stream>>>(rowstart, srcidx, A, B);
  k6_mlp2<<<(NN + 255) / 256, 256, 0, stream>>>(A, B, nn2_w1, nn2_b1, nn2_w2, nn2_b2, Cb, stats2);
  k7_head<<<(NN + 255) / 256, 256, 0, stream>>>(Cb, stats2, bn2_g, bn2_b, fc1_w, fc1_b, fc2_w, fc2_b, out);
}

// Round 4
// 538.743 us; speedup vs baseline: 3.2821x; 1.3901x over previous
//
#include <hip/hip_runtime.h>
#include <cstdint>

#define NN 100000
#define NE 1600000
#define FI 602
#define FIP 640           // padded K for k1 (zero rows 602..639)
#define KH 320            // k-range per half
#define DD 32
#define CC 41
#define BN_EPS 1e-5f
#define SCAN_B 98         // ceil(NN/1024)

__device__ __forceinline__ void atomAdd(float* p, float v) {
#ifdef __HIP_PLATFORM_AMD__
  unsafeAtomicAdd(p, v);
#else
  atomicAdd(p, v);
#endif
}

// ---------------- K0: Mp[640x32] = lin1_w @ nn1_w1 (zero-padded) ; cvec ; zero stats
__global__ __launch_bounds__(256) void k0_prep(
    const float* __restrict__ lin1_w, const float* __restrict__ lin1_b,
    const float* __restrict__ nn1_w1,
    float* __restrict__ Mp, float* __restrict__ cvec,
    float* __restrict__ stats1, float* __restrict__ stats2) {
  int o = blockIdx.x * 256 + threadIdx.x;
  if (o < FIP * DD) {
    int k = o >> 5, j = o & 31;
    float s = 0.f;
    if (k < FI) {
      #pragma unroll 4
      for (int c = 0; c < 2 * DD; ++c) s = fmaf(lin1_w[k * (2 * DD) + c], nn1_w1[c * DD + j], s);
    }
    Mp[o] = s;
  }
  if (blockIdx.x == 0) {
    int t = threadIdx.x;
    if (t < DD) {
      float s = 0.f;
      for (int c = 0; c < 2 * DD; ++c) s = fmaf(lin1_b[c], nn1_w1[c * DD + t], s);
      cvec[t] = s;
    }
    if (t >= 128 && t < 192) stats1[t - 128] = 0.f;
    if (t >= 192) stats2[t - 192] = 0.f;
  }
}

// ---------------- CSR build: histogram -> 3-phase scan -> fill
__global__ __launch_bounds__(256) void k_hist(const int* __restrict__ ei, int* __restrict__ deg) {
  int e = blockIdx.x * 256 + threadIdx.x;
  if (e < NE) atomicAdd(&deg[ei[NE + e]], 1);
}

__global__ __launch_bounds__(1024) void k_scan1(const int* __restrict__ deg, int* __restrict__ bsum) {
  __shared__ int wsum[16];
  int gid = blockIdx.x * 1024 + threadIdx.x;
  int v = (gid < NN) ? deg[gid] : 0;
  #pragma unroll
  for (int off = 1; off < 64; off <<= 1) v += __shfl_xor(v, off);
  int wave = threadIdx.x >> 6, lane = threadIdx.x & 63;
  if (lane == 0) wsum[wave] = v;
  __syncthreads();
  if (threadIdx.x == 0) {
    int s = 0;
    #pragma unroll
    for (int i = 0; i < 16; ++i) s += wsum[i];
    bsum[blockIdx.x] = s;
  }
}

__global__ __launch_bounds__(128) void k_scan2(int* __restrict__ bsum, int* __restrict__ rowstart) {
  __shared__ int ps[128];
  int t = threadIdx.x;
  int v = (t < SCAN_B) ? bsum[t] : 0;
  ps[t] = v;
  __syncthreads();
  #pragma unroll
  for (int off = 1; off < 128; off <<= 1) {
    int u = (t >= off) ? ps[t - off] : 0;
    __syncthreads();
    ps[t] += u;
    __syncthreads();
  }
  if (t < SCAN_B) bsum[t] = ps[t] - v;   // exclusive block offsets
  if (t == 0) rowstart[NN] = NE;
}

__global__ __launch_bounds__(1024) void k_scan3(int* __restrict__ deg_cursor,
                                                const int* __restrict__ bsum,
                                                int* __restrict__ rowstart) {
  __shared__ int ps[1024];
  int gid = blockIdx.x * 1024 + threadIdx.x;
  int t = threadIdx.x;
  int v = (gid < NN) ? deg_cursor[gid] : 0;
  ps[t] = v;
  __syncthreads();
  #pragma unroll
  for (int off = 1; off < 1024; off <<= 1) {
    int u = (t >= off) ? ps[t - off] : 0;
    __syncthreads();
    ps[t] += u;
    __syncthreads();
  }
  int excl = ps[t] - v + bsum[blockIdx.x];
  if (gid < NN) {
    rowstart[gid] = excl;
    deg_cursor[gid] = excl;   // becomes fill cursor
  }
}

__global__ __launch_bounds__(256) void k_fill(const int* __restrict__ ei,
                                              int* __restrict__ cursor,
                                              int* __restrict__ srcidx) {
  int e = blockIdx.x * 256 + threadIdx.x;
  if (e >= NE) return;
  int s = ei[e], d = ei[NE + e];
  int p = atomicAdd(&cursor[d], 1);
  srcidx[p] = s;
}

// ---------------- gather (optionally fused BN on the gathered operand)
template <bool BN>
__global__ __launch_bounds__(256) void k_gather_t(const int* __restrict__ rowstart,
                                                  const int* __restrict__ srcidx,
                                                  const float* __restrict__ src,
                                                  const float* __restrict__ bnp,
                                                  float* __restrict__ agg) {
  int gid = blockIdx.x * 256 + threadIdx.x;
  int n = gid >> 3, q = gid & 7;
  if (n >= NN) return;
  float4 mu, rs, be;
  if (BN) {
    mu = *(const float4*)&bnp[q * 4];
    rs = *(const float4*)&bnp[DD + q * 4];
    be = *(const float4*)&bnp[2 * DD + q * 4];
  }
  int beg = rowstart[n], end = rowstart[n + 1];
  float4 a0 = make_float4(0.f, 0.f, 0.f, 0.f);
  float4 a1 = a0, a2 = a0, a3 = a0;
  int i = beg;
  for (; i + 4 <= end; i += 4) {
    int s0 = srcidx[i], s1 = srcidx[i + 1], s2 = srcidx[i + 2], s3 = srcidx[i + 3];
    float4 v0 = *(const float4*)&src[(size_t)s0 * DD + q * 4];
    float4 v1 = *(const float4*)&src[(size_t)s1 * DD + q * 4];
    float4 v2 = *(const float4*)&src[(size_t)s2 * DD + q * 4];
    float4 v3 = *(const float4*)&src[(size_t)s3 * DD + q * 4];
    if (BN) {
      v0 = make_float4((v0.x - mu.x) * rs.x + be.x, (v0.y - mu.y) * rs.y + be.y,
                       (v0.z - mu.z) * rs.z + be.z, (v0.w - mu.w) * rs.w + be.w);
      v1 = make_float4((v1.x - mu.x) * rs.x + be.x, (v1.y - mu.y) * rs.y + be.y,
                       (v1.z - mu.z) * rs.z + be.z, (v1.w - mu.w) * rs.w + be.w);
      v2 = make_float4((v2.x - mu.x) * rs.x + be.x, (v2.y - mu.y) * rs.y + be.y,
                       (v2.z - mu.z) * rs.z + be.z, (v2.w - mu.w) * rs.w + be.w);
      v3 = make_float4((v3.x - mu.x) * rs.x + be.x, (v3.y - mu.y) * rs.y + be.y,
                       (v3.z - mu.z) * rs.z + be.z, (v3.w - mu.w) * rs.w + be.w);
    }
    a0.x += v0.x; a0.y += v0.y; a0.z += v0.z; a0.w += v0.w;
    a1.x += v1.x; a1.y += v1.y; a1.z += v1.z; a1.w += v1.w;
    a2.x += v2.x; a2.y += v2.y; a2.z += v2.z; a2.w += v2.w;
    a3.x += v3.x; a3.y += v3.y; a3.z += v3.z; a3.w += v3.w;
  }
  for (; i < end; ++i) {
    int s0 = srcidx[i];
    float4 v0 = *(const float4*)&src[(size_t)s0 * DD + q * 4];
    if (BN)
      v0 = make_float4((v0.x - mu.x) * rs.x + be.x, (v0.y - mu.y) * rs.y + be.y,
                       (v0.z - mu.z) * rs.z + be.z, (v0.w - mu.w) * rs.w + be.w);
    a0.x += v0.x; a0.y += v0.y; a0.z += v0.z; a0.w += v0.w;
  }
  float4 r = make_float4(a0.x + a1.x + a2.x + a3.x, a0.y + a1.y + a2.y + a3.y,
                         a0.z + a1.z + a2.z + a3.z, a0.w + a1.w + a2.w + a3.w);
  *(float4*)&agg[(size_t)n * DD + q * 4] = r;
}

// ---------------- K1: z = x @ Mp + cvec
__global__ __launch_bounds__(256) void k1_lin1(
    const float* __restrict__ x, const float* __restrict__ Mp,
    const float* __restrict__ cvec, float* __restrict__ z) {
  __shared__ float xs[2][128][33];
  const int tid = threadIdx.x;
  const int r = tid & 127;
  const int h = tid >> 7;
  const int row = blockIdx.x * 128 + r;
  float acc[DD] = {};
  for (int c = 0; c < 10; ++c) {
    #pragma unroll
    for (int i = 0; i < 16; ++i) {
      int fid = i * 256 + tid;
      int tile = fid >> 11;
      int e = fid & 2047;
      int rr = e >> 4, kp = e & 15;
      int grow = blockIdx.x * 128 + rr;
      int gk = tile * KH + c * 32 + kp * 2;
      float2 v = make_float2(0.f, 0.f);
      if (grow < NN && gk < FI) v = *(const float2*)&x[(size_t)grow * FI + gk];
      xs[tile][rr][kp * 2] = v.x;
      xs[tile][rr][kp * 2 + 1] = v.y;
    }
    __syncthreads();
    #pragma unroll
    for (int kk = 0; kk < 32; ++kk) {
      float xv = xs[h][r][kk];
      int kg = __builtin_amdgcn_readfirstlane(h * KH + c * 32 + kk);
      const float* Mk = Mp + (size_t)kg * DD;
      #pragma unroll
      for (int j = 0; j < DD; ++j) acc[j] = fmaf(xv, Mk[j], acc[j]);
    }
    __syncthreads();
  }
  float* psf = &xs[0][0][0];
  if (h == 1) {
    #pragma unroll
    for (int j = 0; j < DD; ++j) psf[r * 33 + j] = acc[j];
  }
  __syncthreads();
  if (h == 0 && row < NN) {
    #pragma unroll
    for (int j = 0; j < DD; ++j) acc[j] += psf[r * 33 + j] + cvec[j];
    #pragma unroll
    for (int j4 = 0; j4 < 8; ++j4)
      *(float4*)&z[(size_t)row * DD + j4 * 4] =
          make_float4(acc[j4 * 4], acc[j4 * 4 + 1], acc[j4 * 4 + 2], acc[j4 * 4 + 3]);
  }
}

// ---------------- K3: g1 = relu(z+agg+b1) @ w2 + b2 ; stats
__global__ __launch_bounds__(256) void k3_mlp1(
    const float* __restrict__ z, const float* __restrict__ agg,
    const float* __restrict__ w2, const float* __restrict__ b1, const float* __restrict__ b2,
    float* __restrict__ g1, float* __restrict__ stats) {
  __shared__ float us[256][DD + 1];
  __shared__ float w2s[DD][DD];
  __shared__ float ps[4][2 * DD];
  const int tid = threadIdx.x;
  const int n0 = blockIdx.x * 256;
  for (int i = tid; i < DD * DD; i += 256) w2s[i >> 5][i & 31] = w2[i];
  #pragma unroll
  for (int i = 0; i < 32; ++i) {
    int l = tid + i * 256;
    int r = l >> 5, c = l & 31;
    float v = 0.f;
    if (n0 + r < NN) {
      size_t gi = (size_t)(n0 + r) * DD + c;
      v = z[gi] + agg[gi];
    }
    us[r][c] = v;
  }
  __syncthreads();
  float t[DD];
  #pragma unroll
  for (int k = 0; k < DD; ++k) t[k] = fmaxf(us[tid][k] + b1[k], 0.f);
  float g[DD];
  #pragma unroll
  for (int j = 0; j < DD; ++j) g[j] = b2[j];
  #pragma unroll
  for (int k = 0; k < DD; ++k) {
    float tv = t[k];
    #pragma unroll
    for (int j = 0; j < DD; ++j) g[j] = fmaf(tv, w2s[k][j], g[j]);
  }
  bool valid = (n0 + tid) < NN;
  #pragma unroll
  for (int j = 0; j < DD; ++j) us[tid][j] = g[j];
  int wave = tid >> 6, lane = tid & 63;
  #pragma unroll
  for (int j = 0; j < DD; ++j) {
    float v = valid ? g[j] : 0.f;
    float q = v * v;
    #pragma unroll
    for (int off = 1; off < 64; off <<= 1) { v += __shfl_xor(v, off); q += __shfl_xor(q, off); }
    if (lane == 0) { ps[wave][j] = v; ps[wave][DD + j] = q; }
  }
  __syncthreads();
  if (tid < 2 * DD)
    atomAdd(&stats[tid], ps[0][tid] + ps[1][tid] + ps[2][tid] + ps[3][tid]);
  #pragma unroll
  for (int i = 0; i < 32; ++i) {
    int l = tid + i * 256;
    int r = l >> 5, c = l & 31;
    if (n0 + r < NN) g1[(size_t)(n0 + r) * DD + c] = us[r][c];
  }
}

// ---------------- K3b: finalize BN1 params
__global__ void k3b_bn(const float* __restrict__ stats, const float* __restrict__ gamma,
                       const float* __restrict__ beta, float* __restrict__ bnp) {
  int t = threadIdx.x;
  if (t < DD) {
    float mu = stats[t] * (1.f / NN);
    float var = stats[DD + t] * (1.f / NN) - mu * mu;
    bnp[t] = mu;
    bnp[DD + t] = rsqrtf(var + BN_EPS) * gamma[t];
    bnp[2 * DD + t] = beta[t];
  }
}

// ---------------- K6: g2 = relu((bn1(g1)+agg2)@w1+b1)@w2+b2 ; stats2
__global__ __launch_bounds__(256) void k6_mlp2(
    const float* __restrict__ g1, const float* __restrict__ agg,
    const float* __restrict__ bnp,
    const float* __restrict__ w1, const float* __restrict__ b1,
    const float* __restrict__ w2, const float* __restrict__ b2,
    float* __restrict__ g2, float* __restrict__ stats) {
  __shared__ float us[256][DD + 1];
  __shared__ float w1s[DD][DD];
  __shared__ float w2s[DD][DD];
  __shared__ float ps[4][2 * DD];
  const int tid = threadIdx.x;
  const int n0 = blockIdx.x * 256;
  for (int i = tid; i < DD * DD; i += 256) { w1s[i >> 5][i & 31] = w1[i]; w2s[i >> 5][i & 31] = w2[i]; }
  #pragma unroll
  for (int i = 0; i < 32; ++i) {
    int l = tid + i * 256;
    int r = l >> 5, c = l & 31;
    float v = 0.f;
    if (n0 + r < NN) {
      size_t gi = (size_t)(n0 + r) * DD + c;
      v = (g1[gi] - bnp[c]) * bnp[DD + c] + bnp[2 * DD + c] + agg[gi];
    }
    us[r][c] = v;
  }
  __syncthreads();
  float t1[DD];
  #pragma unroll
  for (int j = 0; j < DD; ++j) t1[j] = b1[j];
  #pragma unroll
  for (int k = 0; k < DD; ++k) {
    float uv = us[tid][k];
    #pragma unroll
    for (int j = 0; j < DD; ++j) t1[j] = fmaf(uv, w1s[k][j], t1[j]);
  }
  #pragma unroll
  for (int j = 0; j < DD; ++j) t1[j] = fmaxf(t1[j], 0.f);
  float g[DD];
  #pragma unroll
  for (int j = 0; j < DD; ++j) g[j] = b2[j];
  #pragma unroll
  for (int k = 0; k < DD; ++k) {
    float tv = t1[k];
    #pragma unroll
    for (int j = 0; j < DD; ++j) g[j] = fmaf(tv, w2s[k][j], g[j]);
  }
  bool valid = (n0 + tid) < NN;
  #pragma unroll
  for (int j = 0; j < DD; ++j) us[tid][j] = g[j];
  int wave = tid >> 6, lane = tid & 63;
  #pragma unroll
  for (int j = 0; j < DD; ++j) {
    float v = valid ? g[j] : 0.f;
    float q = v * v;
    #pragma unroll
    for (int off = 1; off < 64; off <<= 1) { v += __shfl_xor(v, off); q += __shfl_xor(q, off); }
    if (lane == 0) { ps[wave][j] = v; ps[wave][DD + j] = q; }
  }
  __syncthreads();
  if (tid < 2 * DD)
    atomAdd(&stats[tid], ps[0][tid] + ps[1][tid] + ps[2][tid] + ps[3][tid]);
  #pragma unroll
  for (int i = 0; i < 32; ++i) {
    int l = tid + i * 256;
    int r = l >> 5, c = l & 31;
    if (n0 + r < NN) g2[(size_t)(n0 + r) * DD + c] = us[r][c];
  }
}

// ---------------- K7: out = relu(bn2(g2)@fc1+b)@fc2+b
__global__ __launch_bounds__(256) void k7_head(
    const float* __restrict__ g2, const float* __restrict__ stats2,
    const float* __restrict__ bn2_g, const float* __restrict__ bn2_b,
    const float* __restrict__ fc1_w, const float* __restrict__ fc1_b,
    const float* __restrict__ fc2_w, const float* __restrict__ fc2_b,
    float* __restrict__ out) {
  __shared__ float buf[256 * 42];
  __shared__ float fc1s[DD * DD];
  __shared__ float fc2s[DD * CC];
  __shared__ float mu2[DD], rsg2[DD], bet2[DD];
  const int tid = threadIdx.x;
  const int n0 = blockIdx.x * 256;
  if (tid < DD) {
    float mu = stats2[tid] * (1.f / NN);
    float var = stats2[DD + tid] * (1.f / NN) - mu * mu;
    mu2[tid] = mu;
    rsg2[tid] = rsqrtf(var + BN_EPS) * bn2_g[tid];
    bet2[tid] = bn2_b[tid];
  }
  for (int i = tid; i < DD * DD; i += 256) fc1s[i] = fc1_w[i];
  for (int i = tid; i < DD * CC; i += 256) fc2s[i] = fc2_w[i];
  __syncthreads();
  #pragma unroll
  for (int i = 0; i < 32; ++i) {
    int l = tid + i * 256;
    int r = l >> 5, c = l & 31;
    float v = 0.f;
    if (n0 + r < NN) v = (g2[(size_t)(n0 + r) * DD + c] - mu2[c]) * rsg2[c] + bet2[c];
    buf[r * 33 + c] = v;
  }
  __syncthreads();
  float t[DD];
  #pragma unroll
  for (int j = 0; j < DD; ++j) t[j] = fc1_b[j];
  #pragma unroll
  for (int k = 0; k < DD; ++k) {
    float uv = buf[tid * 33 + k];
    #pragma unroll
    for (int j = 0; j < DD; ++j) t[j] = fmaf(uv, fc1s[k * DD + j], t[j]);
  }
  #pragma unroll
  for (int j = 0; j < DD; ++j) t[j] = fmaxf(t[j], 0.f);
  float o[CC];
  #pragma unroll
  for (int j = 0; j < CC; ++j) o[j] = fc2_b[j];
  #pragma unroll
  for (int k = 0; k < DD; ++k) {
    float tv = t[k];
    #pragma unroll
    for (int j = 0; j < CC; ++j) o[j] = fmaf(tv, fc2s[k * CC + j], o[j]);
  }
  __syncthreads();
  #pragma unroll
  for (int j = 0; j < CC; ++j) buf[tid * 42 + j] = o[j];
  __syncthreads();
  for (int i = 0; i < CC; ++i) {
    int l = tid + i * 256;
    int r = l / CC, c = l % CC;
    if (n0 + r < NN) out[(size_t)(n0 + r) * CC + c] = buf[r * 42 + c];
  }
}

extern "C" void kernel_launch(void* const* d_in, const int* in_sizes, int n_in,
                              void* d_out, int out_size, void* d_ws, size_t ws_size,
                              hipStream_t stream) {
  const float* x      = (const float*)d_in[0];
  const int*   ei     = (const int*)d_in[1];
  const float* lin1_w = (const float*)d_in[2];
  const float* lin1_b = (const float*)d_in[3];
  const float* nn1_w1 = (const float*)d_in[4];
  const float* nn1_b1 = (const float*)d_in[5];
  const float* nn1_w2 = (const float*)d_in[6];
  const float* nn1_b2 = (const float*)d_in[7];
  const float* bn1_g  = (const float*)d_in[8];
  const float* bn1_b  = (const float*)d_in[9];
  const float* nn2_w1 = (const float*)d_in[10];
  const float* nn2_b1 = (const float*)d_in[11];
  const float* nn2_w2 = (const float*)d_in[12];
  const float* nn2_b2 = (const float*)d_in[13];
  const float* bn2_g  = (const float*)d_in[14];
  const float* bn2_b  = (const float*)d_in[15];
  const float* fc1_w  = (const float*)d_in[16];
  const float* fc1_b  = (const float*)d_in[17];
  const float* fc2_w  = (const float*)d_in[18];
  const float* fc2_b  = (const float*)d_in[19];
  float* out = (float*)d_out;

  float* ws = (float*)d_ws;
  size_t nd = (size_t)NN * DD;
  float* A      = ws;            // z
  float* B      = ws + nd;       // agg1, then agg2
  float* Cb     = ws + 2 * nd;   // g1, then g2
  float* Mp     = ws + 3 * nd;   // 640*32 (padded)
  float* cvec   = Mp + FIP * DD;
  float* stats1 = cvec + 32;
  float* bnp1   = stats1 + 64;
  float* stats2 = bnp1 + 96;
  int*   rowstart = (int*)(stats2 + 64);         // NN+1
  int*   cursor   = rowstart + (NN + 1);         // NN (deg -> cursor)
  int*   srcidx   = cursor + NN;                 // NE
  int*   bsum     = srcidx + NE;                 // SCAN_B

  // CSR build
  hipMemsetAsync(cursor, 0, NN * sizeof(int), stream);
  k_hist<<<(NE + 255) / 256, 256, 0, stream>>>(ei, cursor);
  k_scan1<<<SCAN_B, 1024, 0, stream>>>(cursor, bsum);
  k_scan2<<<1, 128, 0, stream>>>(bsum, rowstart);
  k_scan3<<<SCAN_B, 1024, 0, stream>>>(cursor, bsum, rowstart);
  k_fill<<<(NE + 255) / 256, 256, 0, stream>>>(ei, cursor, srcidx);

  k0_prep<<<(FIP * DD + 255) / 256, 256, 0, stream>>>(lin1_w, lin1_b, nn1_w1, Mp, cvec, stats1, stats2);
  k1_lin1<<<(NN + 127) / 128, 256, 0, stream>>>(x, Mp, cvec, A);
  k_gather_t<false><<<(NN * 8 + 255) / 256, 256, 0, stream>>>(rowstart, srcidx, A, nullptr, B);
  k3_mlp1<<<(NN + 255) / 256, 256, 0, stream>>>(A, B, nn1_w2, nn1_b1, nn1_b2, Cb, stats1);
  k3b_bn<<<1, 64, 0, stream>>>(stats1, bn1_g, bn1_b, bnp1);
  k_gather_t<true><<<(NN * 8 + 255) / 256, 256, 0, stream>>>(rowstart, srcidx, Cb, bnp1, B);
  k6_mlp2<<<(NN + 255) / 256, 256, 0, stream>>>(Cb, B, bnp1, nn2_w1, nn2_b1, nn2_w2, nn2_b2, A, stats2);
  k7_head<<<(NN + 255) / 256, 256, 0, stream>>>(A, stats2, bn2_g, bn2_b, fc1_w, fc1_b, fc2_w, fc2_b, out);
}

// Round 5
// 475.379 us; speedup vs baseline: 3.7195x; 1.1333x over previous
//
#include <hip/hip_runtime.h>
#include <cstdint>

#define NN 100000
#define NE 1600000
#define FI 602
#define FIP 640           // padded K for k1 (zero rows 602..639)
#define DD 32
#define CC 41
#define BN_EPS 1e-5f
#define SCAN_B 98         // ceil(NN/1024)
#define K1CH 16
#define K1NCH 38          // 38*16 = 608 >= 602

__device__ __forceinline__ void atomAdd(float* p, float v) {
#ifdef __HIP_PLATFORM_AMD__
  unsafeAtomicAdd(p, v);
#else
  atomicAdd(p, v);
#endif
}

// ---------------- K0: Mp[640x32] = lin1_w @ nn1_w1 (zero-padded) ; cvec ; zero stats
__global__ __launch_bounds__(256) void k0_prep(
    const float* __restrict__ lin1_w, const float* __restrict__ lin1_b,
    const float* __restrict__ nn1_w1,
    float* __restrict__ Mp, float* __restrict__ cvec,
    float* __restrict__ stats1, float* __restrict__ stats2) {
  int o = blockIdx.x * 256 + threadIdx.x;
  if (o < FIP * DD) {
    int k = o >> 5, j = o & 31;
    float s = 0.f;
    if (k < FI) {
      #pragma unroll 4
      for (int c = 0; c < 2 * DD; ++c) s = fmaf(lin1_w[k * (2 * DD) + c], nn1_w1[c * DD + j], s);
    }
    Mp[o] = s;
  }
  if (blockIdx.x == 0) {
    int t = threadIdx.x;
    if (t < DD) {
      float s = 0.f;
      for (int c = 0; c < 2 * DD; ++c) s = fmaf(lin1_b[c], nn1_w1[c * DD + t], s);
      cvec[t] = s;
    }
    if (t >= 128 && t < 192) stats1[t - 128] = 0.f;
    if (t >= 192) stats2[t - 192] = 0.f;
  }
}

// ---------------- CSR build: histogram -> 3-phase scan -> fill
__global__ __launch_bounds__(256) void k_hist(const int* __restrict__ ei, int* __restrict__ deg) {
  int e = blockIdx.x * 256 + threadIdx.x;
  if (e < NE) atomicAdd(&deg[ei[NE + e]], 1);
}

__global__ __launch_bounds__(1024) void k_scan1(const int* __restrict__ deg, int* __restrict__ bsum) {
  __shared__ int wsum[16];
  int gid = blockIdx.x * 1024 + threadIdx.x;
  int v = (gid < NN) ? deg[gid] : 0;
  #pragma unroll
  for (int off = 1; off < 64; off <<= 1) v += __shfl_xor(v, off);
  int wave = threadIdx.x >> 6, lane = threadIdx.x & 63;
  if (lane == 0) wsum[wave] = v;
  __syncthreads();
  if (threadIdx.x == 0) {
    int s = 0;
    #pragma unroll
    for (int i = 0; i < 16; ++i) s += wsum[i];
    bsum[blockIdx.x] = s;
  }
}

__global__ __launch_bounds__(128) void k_scan2(int* __restrict__ bsum, int* __restrict__ rowstart) {
  __shared__ int ps[128];
  int t = threadIdx.x;
  int v = (t < SCAN_B) ? bsum[t] : 0;
  ps[t] = v;
  __syncthreads();
  #pragma unroll
  for (int off = 1; off < 128; off <<= 1) {
    int u = (t >= off) ? ps[t - off] : 0;
    __syncthreads();
    ps[t] += u;
    __syncthreads();
  }
  if (t < SCAN_B) bsum[t] = ps[t] - v;   // exclusive block offsets
  if (t == 0) rowstart[NN] = NE;
}

__global__ __launch_bounds__(1024) void k_scan3(int* __restrict__ deg_cursor,
                                                const int* __restrict__ bsum,
                                                int* __restrict__ rowstart) {
  __shared__ int ps[1024];
  int gid = blockIdx.x * 1024 + threadIdx.x;
  int t = threadIdx.x;
  int v = (gid < NN) ? deg_cursor[gid] : 0;
  ps[t] = v;
  __syncthreads();
  #pragma unroll
  for (int off = 1; off < 1024; off <<= 1) {
    int u = (t >= off) ? ps[t - off] : 0;
    __syncthreads();
    ps[t] += u;
    __syncthreads();
  }
  int excl = ps[t] - v + bsum[blockIdx.x];
  if (gid < NN) {
    rowstart[gid] = excl;
    deg_cursor[gid] = excl;   // becomes fill cursor
  }
}

__global__ __launch_bounds__(256) void k_fill(const int* __restrict__ ei,
                                              int* __restrict__ cursor,
                                              int* __restrict__ srcidx) {
  int e = blockIdx.x * 256 + threadIdx.x;
  if (e >= NE) return;
  int s = ei[e], d = ei[NE + e];
  int p = atomicAdd(&cursor[d], 1);
  srcidx[p] = s;
}

// ---------------- gather (optionally fused BN on the gathered operand)
template <bool BN>
__global__ __launch_bounds__(256) void k_gather_t(const int* __restrict__ rowstart,
                                                  const int* __restrict__ srcidx,
                                                  const float* __restrict__ src,
                                                  const float* __restrict__ bnp,
                                                  float* __restrict__ agg) {
  int gid = blockIdx.x * 256 + threadIdx.x;
  int n = gid >> 3, q = gid & 7;
  if (n >= NN) return;
  float4 mu, rs, be;
  if (BN) {
    mu = *(const float4*)&bnp[q * 4];
    rs = *(const float4*)&bnp[DD + q * 4];
    be = *(const float4*)&bnp[2 * DD + q * 4];
  }
  int beg = rowstart[n], end = rowstart[n + 1];
  float4 a0 = make_float4(0.f, 0.f, 0.f, 0.f);
  float4 a1 = a0, a2 = a0, a3 = a0;
  int i = beg;
  for (; i + 4 <= end; i += 4) {
    int s0 = srcidx[i], s1 = srcidx[i + 1], s2 = srcidx[i + 2], s3 = srcidx[i + 3];
    float4 v0 = *(const float4*)&src[(size_t)s0 * DD + q * 4];
    float4 v1 = *(const float4*)&src[(size_t)s1 * DD + q * 4];
    float4 v2 = *(const float4*)&src[(size_t)s2 * DD + q * 4];
    float4 v3 = *(const float4*)&src[(size_t)s3 * DD + q * 4];
    if (BN) {
      v0 = make_float4((v0.x - mu.x) * rs.x + be.x, (v0.y - mu.y) * rs.y + be.y,
                       (v0.z - mu.z) * rs.z + be.z, (v0.w - mu.w) * rs.w + be.w);
      v1 = make_float4((v1.x - mu.x) * rs.x + be.x, (v1.y - mu.y) * rs.y + be.y,
                       (v1.z - mu.z) * rs.z + be.z, (v1.w - mu.w) * rs.w + be.w);
      v2 = make_float4((v2.x - mu.x) * rs.x + be.x, (v2.y - mu.y) * rs.y + be.y,
                       (v2.z - mu.z) * rs.z + be.z, (v2.w - mu.w) * rs.w + be.w);
      v3 = make_float4((v3.x - mu.x) * rs.x + be.x, (v3.y - mu.y) * rs.y + be.y,
                       (v3.z - mu.z) * rs.z + be.z, (v3.w - mu.w) * rs.w + be.w);
    }
    a0.x += v0.x; a0.y += v0.y; a0.z += v0.z; a0.w += v0.w;
    a1.x += v1.x; a1.y += v1.y; a1.z += v1.z; a1.w += v1.w;
    a2.x += v2.x; a2.y += v2.y; a2.z += v2.z; a2.w += v2.w;
    a3.x += v3.x; a3.y += v3.y; a3.z += v3.z; a3.w += v3.w;
  }
  for (; i < end; ++i) {
    int s0 = srcidx[i];
    float4 v0 = *(const float4*)&src[(size_t)s0 * DD + q * 4];
    if (BN)
      v0 = make_float4((v0.x - mu.x) * rs.x + be.x, (v0.y - mu.y) * rs.y + be.y,
                       (v0.z - mu.z) * rs.z + be.z, (v0.w - mu.w) * rs.w + be.w);
    a0.x += v0.x; a0.y += v0.y; a0.z += v0.z; a0.w += v0.w;
  }
  float4 r = make_float4(a0.x + a1.x + a2.x + a3.x, a0.y + a1.y + a2.y + a3.y,
                         a0.z + a1.z + a2.z + a3.z, a0.w + a1.w + a2.w + a3.w);
  *(float4*)&agg[(size_t)n * DD + q * 4] = r;
}

// ---------------- K1 v3: z = x @ Mp + cvec
// 512 threads, 128 rows/block. Wave w: j-quarter q=w>>1 (8 cols), row-half w&1.
// Register-prefetch next k-chunk while computing current; double-buffered LDS;
// M rows wave-uniform -> scalar broadcast loads.
__global__ __launch_bounds__(512) void k1_lin1(
    const float* __restrict__ x, const float* __restrict__ Mp,
    const float* __restrict__ cvec, float* __restrict__ z) {
  __shared__ float xs[2][128][K1CH + 1];
  const int tid = threadIdx.x;
  const int wave = tid >> 6, lane = tid & 63;
  const int q = wave >> 1;                  // 0..3 -> cols q*8..q*8+7
  const int rloc = (wave & 1) * 64 + lane;  // 0..127
  const int row0 = blockIdx.x * 128;
  const int row = row0 + rloc;
  const int rr = tid >> 2, kq = tid & 3;    // staging: one float4 per thread
  const int gr = row0 + rr;
  float acc[8] = {};
  float4 pa;

  // prologue: chunk 0 (gk <= 15, no tail guard)
  {
    int gk = kq * 4;
    pa = make_float4(0.f, 0.f, 0.f, 0.f);
    if (gr < NN) pa = *(const float4*)&x[(size_t)gr * FI + gk];
    float* p0 = &xs[0][rr][kq * 4];
    p0[0] = pa.x; p0[1] = pa.y; p0[2] = pa.z; p0[3] = pa.w;
  }

  int cur = 0;
  for (int c = 0; c < K1NCH; ++c) {
    if (c + 1 < K1NCH) {
      int gk = (c + 1) * K1CH + kq * 4;
      pa = make_float4(0.f, 0.f, 0.f, 0.f);
      if (gr < NN) {
        if (gk + 3 < FI) {
          pa = *(const float4*)&x[(size_t)gr * FI + gk];
        } else {
          if (gk + 0 < FI) pa.x = x[(size_t)gr * FI + gk + 0];
          if (gk + 1 < FI) pa.y = x[(size_t)gr * FI + gk + 1];
          if (gk + 2 < FI) pa.z = x[(size_t)gr * FI + gk + 2];
        }
      }
    }
    __syncthreads();   // buf[cur] fully written
    const int kbase = c * K1CH;
    #pragma unroll
    for (int kk = 0; kk < K1CH; ++kk) {
      float xv = xs[cur][rloc][kk];
      int moff = __builtin_amdgcn_readfirstlane((kbase + kk) * DD + q * 8);
      const float* __restrict__ Mk = Mp + moff;
      #pragma unroll
      for (int j = 0; j < 8; ++j) acc[j] = fmaf(xv, Mk[j], acc[j]);
    }
    if (c + 1 < K1NCH) {
      int nxt = cur ^ 1;
      float* p0 = &xs[nxt][rr][kq * 4];
      p0[0] = pa.x; p0[1] = pa.y; p0[2] = pa.z; p0[3] = pa.w;
    }
    cur ^= 1;
  }

  if (row < NN) {
    const float* cv = cvec + q * 8;
    float* zp = &z[(size_t)row * DD + q * 8];
    *(float4*)&zp[0] = make_float4(acc[0] + cv[0], acc[1] + cv[1], acc[2] + cv[2], acc[3] + cv[3]);
    *(float4*)&zp[4] = make_float4(acc[4] + cv[4], acc[5] + cv[5], acc[6] + cv[6], acc[7] + cv[7]);
  }
}

// ---------------- K3: g1 = relu(z+agg+b1) @ w2 + b2 ; stats
__global__ __launch_bounds__(256) void k3_mlp1(
    const float* __restrict__ z, const float* __restrict__ agg,
    const float* __restrict__ w2, const float* __restrict__ b1, const float* __restrict__ b2,
    float* __restrict__ g1, float* __restrict__ stats) {
  __shared__ float us[256][DD + 1];
  __shared__ float w2s[DD][DD];
  __shared__ float ps[4][2 * DD];
  const int tid = threadIdx.x;
  const int n0 = blockIdx.x * 256;
  for (int i = tid; i < DD * DD; i += 256) w2s[i >> 5][i & 31] = w2[i];
  #pragma unroll
  for (int i = 0; i < 32; ++i) {
    int l = tid + i * 256;
    int r = l >> 5, c = l & 31;
    float v = 0.f;
    if (n0 + r < NN) {
      size_t gi = (size_t)(n0 + r) * DD + c;
      v = z[gi] + agg[gi];
    }
    us[r][c] = v;
  }
  __syncthreads();
  float t[DD];
  #pragma unroll
  for (int k = 0; k < DD; ++k) t[k] = fmaxf(us[tid][k] + b1[k], 0.f);
  float g[DD];
  #pragma unroll
  for (int j = 0; j < DD; ++j) g[j] = b2[j];
  #pragma unroll
  for (int k = 0; k < DD; ++k) {
    float tv = t[k];
    #pragma unroll
    for (int j = 0; j < DD; ++j) g[j] = fmaf(tv, w2s[k][j], g[j]);
  }
  bool valid = (n0 + tid) < NN;
  #pragma unroll
  for (int j = 0; j < DD; ++j) us[tid][j] = g[j];
  int wave = tid >> 6, lane = tid & 63;
  #pragma unroll
  for (int j = 0; j < DD; ++j) {
    float v = valid ? g[j] : 0.f;
    float qq = v * v;
    #pragma unroll
    for (int off = 1; off < 64; off <<= 1) { v += __shfl_xor(v, off); qq += __shfl_xor(qq, off); }
    if (lane == 0) { ps[wave][j] = v; ps[wave][DD + j] = qq; }
  }
  __syncthreads();
  if (tid < 2 * DD)
    atomAdd(&stats[tid], ps[0][tid] + ps[1][tid] + ps[2][tid] + ps[3][tid]);
  #pragma unroll
  for (int i = 0; i < 32; ++i) {
    int l = tid + i * 256;
    int r = l >> 5, c = l & 31;
    if (n0 + r < NN) g1[(size_t)(n0 + r) * DD + c] = us[r][c];
  }
}

// ---------------- K3b: finalize BN1 params
__global__ void k3b_bn(const float* __restrict__ stats, const float* __restrict__ gamma,
                       const float* __restrict__ beta, float* __restrict__ bnp) {
  int t = threadIdx.x;
  if (t < DD) {
    float mu = stats[t] * (1.f / NN);
    float var = stats[DD + t] * (1.f / NN) - mu * mu;
    bnp[t] = mu;
    bnp[DD + t] = rsqrtf(var + BN_EPS) * gamma[t];
    bnp[2 * DD + t] = beta[t];
  }
}

// ---------------- K6: g2 = relu((bn1(g1)+agg2)@w1+b1)@w2+b2 ; stats2
__global__ __launch_bounds__(256) void k6_mlp2(
    const float* __restrict__ g1, const float* __restrict__ agg,
    const float* __restrict__ bnp,
    const float* __restrict__ w1, const float* __restrict__ b1,
    const float* __restrict__ w2, const float* __restrict__ b2,
    float* __restrict__ g2, float* __restrict__ stats) {
  __shared__ float us[256][DD + 1];
  __shared__ float w1s[DD][DD];
  __shared__ float w2s[DD][DD];
  __shared__ float ps[4][2 * DD];
  const int tid = threadIdx.x;
  const int n0 = blockIdx.x * 256;
  for (int i = tid; i < DD * DD; i += 256) { w1s[i >> 5][i & 31] = w1[i]; w2s[i >> 5][i & 31] = w2[i]; }
  #pragma unroll
  for (int i = 0; i < 32; ++i) {
    int l = tid + i * 256;
    int r = l >> 5, c = l & 31;
    float v = 0.f;
    if (n0 + r < NN) {
      size_t gi = (size_t)(n0 + r) * DD + c;
      v = (g1[gi] - bnp[c]) * bnp[DD + c] + bnp[2 * DD + c] + agg[gi];
    }
    us[r][c] = v;
  }
  __syncthreads();
  float t1[DD];
  #pragma unroll
  for (int j = 0; j < DD; ++j) t1[j] = b1[j];
  #pragma unroll
  for (int k = 0; k < DD; ++k) {
    float uv = us[tid][k];
    #pragma unroll
    for (int j = 0; j < DD; ++j) t1[j] = fmaf(uv, w1s[k][j], t1[j]);
  }
  #pragma unroll
  for (int j = 0; j < DD; ++j) t1[j] = fmaxf(t1[j], 0.f);
  float g[DD];
  #pragma unroll
  for (int j = 0; j < DD; ++j) g[j] = b2[j];
  #pragma unroll
  for (int k = 0; k < DD; ++k) {
    float tv = t1[k];
    #pragma unroll
    for (int j = 0; j < DD; ++j) g[j] = fmaf(tv, w2s[k][j], g[j]);
  }
  bool valid = (n0 + tid) < NN;
  #pragma unroll
  for (int j = 0; j < DD; ++j) us[tid][j] = g[j];
  int wave = tid >> 6, lane = tid & 63;
  #pragma unroll
  for (int j = 0; j < DD; ++j) {
    float v = valid ? g[j] : 0.f;
    float qq = v * v;
    #pragma unroll
    for (int off = 1; off < 64; off <<= 1) { v += __shfl_xor(v, off); qq += __shfl_xor(qq, off); }
    if (lane == 0) { ps[wave][j] = v; ps[wave][DD + j] = qq; }
  }
  __syncthreads();
  if (tid < 2 * DD)
    atomAdd(&stats[tid], ps[0][tid] + ps[1][tid] + ps[2][tid] + ps[3][tid]);
  #pragma unroll
  for (int i = 0; i < 32; ++i) {
    int l = tid + i * 256;
    int r = l >> 5, c = l & 31;
    if (n0 + r < NN) g2[(size_t)(n0 + r) * DD + c] = us[r][c];
  }
}

// ---------------- K7: out = relu(bn2(g2)@fc1+b)@fc2+b
__global__ __launch_bounds__(256) void k7_head(
    const float* __restrict__ g2, const float* __restrict__ stats2,
    const float* __restrict__ bn2_g, const float* __restrict__ bn2_b,
    const float* __restrict__ fc1_w, const float* __restrict__ fc1_b,
    const float* __restrict__ fc2_w, const float* __restrict__ fc2_b,
    float* __restrict__ out) {
  __shared__ float buf[256 * 42];
  __shared__ float fc1s[DD * DD];
  __shared__ float fc2s[DD * CC];
  __shared__ float mu2[DD], rsg2[DD], bet2[DD];
  const int tid = threadIdx.x;
  const int n0 = blockIdx.x * 256;
  if (tid < DD) {
    float mu = stats2[tid] * (1.f / NN);
    float var = stats2[DD + tid] * (1.f / NN) - mu * mu;
    mu2[tid] = mu;
    rsg2[tid] = rsqrtf(var + BN_EPS) * bn2_g[tid];
    bet2[tid] = bn2_b[tid];
  }
  for (int i = tid; i < DD * DD; i += 256) fc1s[i] = fc1_w[i];
  for (int i = tid; i < DD * CC; i += 256) fc2s[i] = fc2_w[i];
  __syncthreads();
  #pragma unroll
  for (int i = 0; i < 32; ++i) {
    int l = tid + i * 256;
    int r = l >> 5, c = l & 31;
    float v = 0.f;
    if (n0 + r < NN) v = (g2[(size_t)(n0 + r) * DD + c] - mu2[c]) * rsg2[c] + bet2[c];
    buf[r * 33 + c] = v;
  }
  __syncthreads();
  float t[DD];
  #pragma unroll
  for (int j = 0; j < DD; ++j) t[j] = fc1_b[j];
  #pragma unroll
  for (int k = 0; k < DD; ++k) {
    float uv = buf[tid * 33 + k];
    #pragma unroll
    for (int j = 0; j < DD; ++j) t[j] = fmaf(uv, fc1s[k * DD + j], t[j]);
  }
  #pragma unroll
  for (int j = 0; j < DD; ++j) t[j] = fmaxf(t[j], 0.f);
  float o[CC];
  #pragma unroll
  for (int j = 0; j < CC; ++j) o[j] = fc2_b[j];
  #pragma unroll
  for (int k = 0; k < DD; ++k) {
    float tv = t[k];
    #pragma unroll
    for (int j = 0; j < CC; ++j) o[j] = fmaf(tv, fc2s[k * CC + j], o[j]);
  }
  __syncthreads();
  #pragma unroll
  for (int j = 0; j < CC; ++j) buf[tid * 42 + j] = o[j];
  __syncthreads();
  for (int i = 0; i < CC; ++i) {
    int l = tid + i * 256;
    int r = l / CC, c = l % CC;
    if (n0 + r < NN) out[(size_t)(n0 + r) * CC + c] = buf[r * 42 + c];
  }
}

extern "C" void kernel_launch(void* const* d_in, const int* in_sizes, int n_in,
                              void* d_out, int out_size, void* d_ws, size_t ws_size,
                              hipStream_t stream) {
  const float* x      = (const float*)d_in[0];
  const int*   ei     = (const int*)d_in[1];
  const float* lin1_w = (const float*)d_in[2];
  const float* lin1_b = (const float*)d_in[3];
  const float* nn1_w1 = (const float*)d_in[4];
  const float* nn1_b1 = (const float*)d_in[5];
  const float* nn1_w2 = (const float*)d_in[6];
  const float* nn1_b2 = (const float*)d_in[7];
  const float* bn1_g  = (const float*)d_in[8];
  const float* bn1_b  = (const float*)d_in[9];
  const float* nn2_w1 = (const float*)d_in[10];
  const float* nn2_b1 = (const float*)d_in[11];
  const float* nn2_w2 = (const float*)d_in[12];
  const float* nn2_b2 = (const float*)d_in[13];
  const float* bn2_g  = (const float*)d_in[14];
  const float* bn2_b  = (const float*)d_in[15];
  const float* fc1_w  = (const float*)d_in[16];
  const float* fc1_b  = (const float*)d_in[17];
  const float* fc2_w  = (const float*)d_in[18];
  const float* fc2_b  = (const float*)d_in[19];
  float* out = (float*)d_out;

  float* ws = (float*)d_ws;
  size_t nd = (size_t)NN * DD;
  float* A      = ws;            // z
  float* B      = ws + nd;       // agg1, then agg2
  float* Cb     = ws + 2 * nd;   // g1, then g2
  float* Mp     = ws + 3 * nd;   // 640*32 (padded)
  float* cvec   = Mp + FIP * DD;
  float* stats1 = cvec + 32;
  float* bnp1   = stats1 + 64;
  float* stats2 = bnp1 + 96;
  int*   rowstart = (int*)(stats2 + 64);         // NN+1
  int*   cursor   = rowstart + (NN + 1);         // NN (deg -> cursor)
  int*   srcidx   = cursor + NN;                 // NE
  int*   bsum     = srcidx + NE;                 // SCAN_B

  // CSR build
  hipMemsetAsync(cursor, 0, NN * sizeof(int), stream);
  k_hist<<<(NE + 255) / 256, 256, 0, stream>>>(ei, cursor);
  k_scan1<<<SCAN_B, 1024, 0, stream>>>(cursor, bsum);
  k_scan2<<<1, 128, 0, stream>>>(bsum, rowstart);
  k_scan3<<<SCAN_B, 1024, 0, stream>>>(cursor, bsum, rowstart);
  k_fill<<<(NE + 255) / 256, 256, 0, stream>>>(ei, cursor, srcidx);

  k0_prep<<<(FIP * DD + 255) / 256, 256, 0, stream>>>(lin1_w, lin1_b, nn1_w1, Mp, cvec, stats1, stats2);
  k1_lin1<<<(NN + 127) / 128, 512, 0, stream>>>(x, Mp, cvec, A);
  k_gather_t<false><<<(NN * 8 + 255) / 256, 256, 0, stream>>>(rowstart, srcidx, A, nullptr, B);
  k3_mlp1<<<(NN + 255) / 256, 256, 0, stream>>>(A, B, nn1_w2, nn1_b1, nn1_b2, Cb, stats1);
  k3b_bn<<<1, 64, 0, stream>>>(stats1, bn1_g, bn1_b, bnp1);
  k_gather_t<true><<<(NN * 8 + 255) / 256, 256, 0, stream>>>(rowstart, srcidx, Cb, bnp1, B);
  k6_mlp2<<<(NN + 255) / 256, 256, 0, stream>>>(Cb, B, bnp1, nn2_w1, nn2_b1, nn2_w2, nn2_b2, A, stats2);
  k7_head<<<(NN + 255) / 256, 256, 0, stream>>>(A, stats2, bn2_g, bn2_b, fc1_w, fc1_b, fc2_w, fc2_b, out);
}